// Round 8
// baseline (332.451 us; speedup 1.0000x reference)
//
#include <hip/hip_runtime.h>

#define N_NODES 50000
#define N_EDGES 600000
#define B_GRAPHS 64
#define DH 128
#define PFEAT 32
#define NCLS 2
#define SCAN_BLOCKS ((N_NODES + 255) / 256)   // 196
#define NPAD (N_NODES + 128)                  // row padding for OOB-safe MFMA loads
#define NCVT4 (N_NODES * 128 / 4)             // 1,600,000
#define WELEMS (384 * 128)                    // 49,152
#define GEMM_GRID ((N_NODES + 63) / 64)       // 782

typedef __attribute__((ext_vector_type(8))) short short8v;
typedef __attribute__((ext_vector_type(4))) float float4v;
typedef __attribute__((ext_vector_type(4))) unsigned int uint4v;

__device__ __forceinline__ unsigned int f2bf(float f) {
    unsigned int u = __float_as_uint(f);
    return (u + 0x7FFFu + ((u >> 16) & 1u)) >> 16;   // RNE
}
__device__ __forceinline__ float bflo(unsigned int p) { return __uint_as_float(p << 16); }
__device__ __forceinline__ float bfhi(unsigned int p) { return __uint_as_float(p & 0xFFFF0000u); }

// ---------- fused init: zero scratch + h->bf16 + W1/W2 transpose-convert ----------
__global__ void k_init(const float* __restrict__ h, unsigned short* __restrict__ h_bf,
                       const float* __restrict__ W1, const float* __restrict__ W2,
                       unsigned short* __restrict__ Wt1, unsigned short* __restrict__ Wt2,
                       int* __restrict__ deg, float* __restrict__ gsum,
                       int* __restrict__ gstart, int* __restrict__ done) {
    int t = blockIdx.x * 256 + threadIdx.x;
    if (t < NCVT4) {
        float4 v = ((const float4*)h)[t];
        unsigned int lo = f2bf(v.x) | (f2bf(v.y) << 16);
        unsigned int hi = f2bf(v.z) | (f2bf(v.w) << 16);
        uint2 r; r.x = lo; r.y = hi;
        ((uint2*)h_bf)[t] = r;
    }
    if (t < 2 * WELEMS) {
        bool second = (t >= WELEMS);
        int idx = second ? t - WELEMS : t;
        const float* W = second ? W2 : W1;
        unsigned short* Wt = second ? Wt2 : Wt1;
        int k = idx >> 7, c = idx & 127;
        Wt[c * 384 + k] = (unsigned short)f2bf(W[idx]);
    }
    if (t < N_NODES) deg[t] = 0;
    if (t < B_GRAPHS * DH) gsum[t] = 0.f;
    if (t < B_GRAPHS) gstart[t] = -1;
    if (t == 0) *done = 0;
}

// ---------- fused: degree atomics (saving bucket positions) + graph run-starts ----------
__global__ void k_deg_bound(const int* __restrict__ dst, const int* __restrict__ gid,
                            int* __restrict__ deg, int* __restrict__ epos,
                            int* __restrict__ gstart) {
    int t = blockIdx.x * 256 + threadIdx.x;
    if (t < N_EDGES) {
        int pos = atomicAdd(&deg[dst[t]], 1);
        epos[t] = pos;
    }
    int n = t - N_EDGES;
    if (n >= 0 && n < N_NODES) {
        int g = gid[n];
        if (n == 0 || gid[n - 1] != g) gstart[g] = n;
    }
}

// ---------- fused: norm + per-block degree sums ----------
__global__ void k_norm_bsum(const int* __restrict__ deg, float* __restrict__ norm,
                            int* __restrict__ bsum) {
    __shared__ int s[256];
    int i = blockIdx.x * 256 + threadIdx.x;
    int d = (i < N_NODES) ? deg[i] : 0;
    if (i < N_NODES) norm[i] = rsqrtf((float)(d < 1 ? 1 : d));
    s[threadIdx.x] = d;
    __syncthreads();
    for (int off = 128; off > 0; off >>= 1) {
        if (threadIdx.x < off) s[threadIdx.x] += s[threadIdx.x + off];
        __syncthreads();
    }
    if (threadIdx.x == 0) bsum[blockIdx.x] = s[0];
}

// ---------- scan: each block redundantly scans 196 block-sums in LDS + local scan ----------
__global__ void k_scan2(const int* __restrict__ deg, const int* __restrict__ bsum,
                        int* __restrict__ row_ptr) {
    __shared__ int sb[256];
    __shared__ int s[256];
    int bv = (threadIdx.x < SCAN_BLOCKS) ? bsum[threadIdx.x] : 0;
    sb[threadIdx.x] = bv;
    int i = blockIdx.x * 256 + threadIdx.x;
    int v = (i < N_NODES) ? deg[i] : 0;
    s[threadIdx.x] = v;
    __syncthreads();
    for (int off = 1; off < 256; off <<= 1) {
        int tb = (threadIdx.x >= off) ? sb[threadIdx.x - off] : 0;
        int t = (threadIdx.x >= off) ? s[threadIdx.x - off] : 0;
        __syncthreads();
        sb[threadIdx.x] += tb;
        s[threadIdx.x] += t;
        __syncthreads();
    }
    int block_off = (blockIdx.x == 0) ? 0 : sb[blockIdx.x - 1];
    if (i < N_NODES) row_ptr[i + 1] = s[threadIdx.x] + block_off;
    if (i == 0) row_ptr[0] = 0;
}

// ---------- scatter edges into CSR buckets (no atomics: positions precomputed) ----------
__global__ void k_scatter(const int* __restrict__ src, const int* __restrict__ dst,
                          const int* __restrict__ row_ptr, const int* __restrict__ epos,
                          int* __restrict__ col) {
    int e = blockIdx.x * blockDim.x + threadIdx.x;
    if (e < N_EDGES) {
        int d = dst[e];
        col[row_ptr[d] + epos[e]] = src[e];
    }
}

// ---------- SpMM hop (bf16 in/out, fp32 accumulate) ----------
__global__ __launch_bounds__(256) void k_spmm(const unsigned short* __restrict__ fin,
                                              const float* __restrict__ norm,
                                              const int* __restrict__ row_ptr,
                                              const int* __restrict__ col,
                                              unsigned short* __restrict__ fout) {
    int wave = threadIdx.x >> 6;
    int lane = threadIdx.x & 63;
    int grp = lane >> 4;
    int l15 = lane & 15;
    int v = blockIdx.x * 4 + wave;
    if (v >= N_NODES) return;
    int beg = row_ptr[v], end = row_ptr[v + 1];

    float a0[8], a1[8], a2[8], a3[8];
#pragma unroll
    for (int j = 0; j < 8; ++j) { a0[j] = 0.f; a1[j] = 0.f; a2[j] = 0.f; a3[j] = 0.f; }

    for (int base = beg; base < end; base += 16) {
        int e0 = base + grp;
        int e1 = e0 + 4, e2 = e0 + 8, e3 = e0 + 12;
        int last = end - 1;
        int c0 = (e0 < end) ? e0 : last;
        int c1 = (e1 < end) ? e1 : last;
        int c2 = (e2 < end) ? e2 : last;
        int c3 = (e3 < end) ? e3 : last;
        int u0 = col[c0], u1 = col[c1], u2 = col[c2], u3 = col[c3];
        uint4v r0 = *(const uint4v*)(fin + (size_t)u0 * 128 + l15 * 8);
        uint4v r1 = *(const uint4v*)(fin + (size_t)u1 * 128 + l15 * 8);
        uint4v r2 = *(const uint4v*)(fin + (size_t)u2 * 128 + l15 * 8);
        uint4v r3 = *(const uint4v*)(fin + (size_t)u3 * 128 + l15 * 8);
        float w0 = (e0 < end) ? norm[u0] : 0.f;
        float w1 = (e1 < end) ? norm[u1] : 0.f;
        float w2 = (e2 < end) ? norm[u2] : 0.f;
        float w3 = (e3 < end) ? norm[u3] : 0.f;
#pragma unroll
        for (int q = 0; q < 4; ++q) {
            a0[2 * q]     = fmaf(bflo(r0[q]), w0, a0[2 * q]);
            a0[2 * q + 1] = fmaf(bfhi(r0[q]), w0, a0[2 * q + 1]);
            a1[2 * q]     = fmaf(bflo(r1[q]), w1, a1[2 * q]);
            a1[2 * q + 1] = fmaf(bfhi(r1[q]), w1, a1[2 * q + 1]);
            a2[2 * q]     = fmaf(bflo(r2[q]), w2, a2[2 * q]);
            a2[2 * q + 1] = fmaf(bfhi(r2[q]), w2, a2[2 * q + 1]);
            a3[2 * q]     = fmaf(bflo(r3[q]), w3, a3[2 * q]);
            a3[2 * q + 1] = fmaf(bfhi(r3[q]), w3, a3[2 * q + 1]);
        }
    }

#pragma unroll
    for (int j = 0; j < 8; ++j) {
        float s = (a0[j] + a1[j]) + (a2[j] + a3[j]);
        s += __shfl_xor(s, 16, 64);
        s += __shfl_xor(s, 32, 64);
        a0[j] = s;
    }
    if (grp == 0) {
        float nv = norm[v];
        uint4v o;
#pragma unroll
        for (int q = 0; q < 4; ++q)
            o[q] = f2bf(a0[2 * q] * nv) | (f2bf(a0[2 * q + 1] * nv) << 16);
        *(uint4v*)(fout + (size_t)v * 128 + l15 * 8) = o;
    }
}

// ---------- bf16 MFMA GEMM v2: wave = 16 rows x 128 cols (2x parallelism) ----------
// Block = 256 thr = 4 waves = 64 rows. grid = 782. Optional fused pool + final.
template <bool RELU, bool POOL>
__global__ __launch_bounds__(256) void k_gemm_mfma(const unsigned short* __restrict__ A0,
                                                   const unsigned short* __restrict__ A1,
                                                   const unsigned short* __restrict__ A2,
                                                   const unsigned short* __restrict__ Wt,
                                                   const float* __restrict__ bias,
                                                   unsigned short* __restrict__ out,
                                                   const int* __restrict__ gid,
                                                   float* __restrict__ gsum,
                                                   int* __restrict__ done,
                                                   const int* __restrict__ gstart,
                                                   const float* __restrict__ b2,
                                                   const float* __restrict__ perm,
                                                   const float* __restrict__ Wc,
                                                   const float* __restrict__ bc,
                                                   float* __restrict__ fout) {
    __shared__ float red4[4][128];
    __shared__ int lastFlag;
    int tid = threadIdx.x;
    int lane = tid & 63;
    int wid = tid >> 6;
    int l15 = lane & 15;
    int lk = lane >> 4;                 // 0..3
    int n0 = blockIdx.x * 64;
    int rbase = n0 + wid * 16;

    float4v acc[8];
#pragma unroll
    for (int ct = 0; ct < 8; ++ct)
#pragma unroll
        for (int i = 0; i < 4; ++i) acc[ct][i] = 0.f;

    const unsigned short* Aseg[3] = {A0, A1, A2};
#pragma unroll
    for (int ks = 0; ks < 12; ++ks) {
        const unsigned short* A = Aseg[ks >> 2];
        int kloc = (ks & 3) * 32 + lk * 8;
        short8v a = *(const short8v*)(A + (size_t)(rbase + l15) * 128 + kloc);
        const unsigned short* wp = Wt + (size_t)l15 * 384 + ks * 32 + lk * 8;
#pragma unroll
        for (int ct = 0; ct < 8; ++ct) {
            short8v b = *(const short8v*)(wp + (size_t)ct * 16 * 384);
            acc[ct] = __builtin_amdgcn_mfma_f32_16x16x32_bf16(a, b, acc[ct], 0, 0, 0);
        }
    }

    if (!POOL) {
        // epilogue: + bias, relu, bf16 store. C/D: col=lane&15, row=(lane>>4)*4+i
        float bj[8];
#pragma unroll
        for (int ct = 0; ct < 8; ++ct) bj[ct] = bias[ct * 16 + l15];
#pragma unroll
        for (int i = 0; i < 4; ++i) {
            int row = rbase + lk * 4 + i;
            if (row < N_NODES) {
#pragma unroll
                for (int ct = 0; ct < 8; ++ct) {
                    float v = acc[ct][i] + bj[ct];
                    if (RELU) v = fmaxf(v, 0.f);
                    out[(size_t)row * 128 + ct * 16 + l15] = (unsigned short)f2bf(v);
                }
            }
        }
    } else {
        // fused mean-pool numerator (bias deferred to final)
        int gr[4];
#pragma unroll
        for (int i = 0; i < 4; ++i) {
            int row = rbase + lk * 4 + i;
            gr[i] = (row < N_NODES) ? gid[row] : -1;
        }
        int lastrow = n0 + 63;
        if (lastrow >= N_NODES) lastrow = N_NODES - 1;
        int gfirst = gid[n0 < N_NODES ? n0 : N_NODES - 1];
        int glast = gid[lastrow];
        for (int g = gfirst; g <= glast; ++g) {
            float p[8];
#pragma unroll
            for (int ct = 0; ct < 8; ++ct) {
                float s = 0.f;
#pragma unroll
                for (int i = 0; i < 4; ++i)
                    if (gr[i] == g) s += acc[ct][i];
                p[ct] = s;
            }
#pragma unroll
            for (int ct = 0; ct < 8; ++ct) {
                p[ct] += __shfl_xor(p[ct], 16, 64);
                p[ct] += __shfl_xor(p[ct], 32, 64);
            }
            if (lane < 16) {
#pragma unroll
                for (int ct = 0; ct < 8; ++ct) red4[wid][ct * 16 + lane] = p[ct];
            }
            __syncthreads();
            if (tid < 128) {
                float s = red4[0][tid] + red4[1][tid] + red4[2][tid] + red4[3][tid];
                atomicAdd(&gsum[g * 128 + tid], s);
            }
            __syncthreads();
        }

        // ---- last-block fused final ----
        __threadfence();
        if (tid == 0) {
            int old = atomicAdd(done, 1);
            lastFlag = (old == (int)gridDim.x - 1) ? 1 : 0;
        }
        __syncthreads();
        if (lastFlag) {
            __threadfence();   // acquire: all other blocks' gsum atomics visible
            if (tid < B_GRAPHS * NCLS) {
                int b = tid >> 1, c = tid & 1;
                int s = gstart[b];
                float cf = 1.f;
                bool nonempty = (s >= 0);
                if (nonempty) {
                    int nxt = N_NODES;
                    for (int j = b + 1; j < B_GRAPHS; ++j) {
                        int sj = gstart[j];
                        if (sj >= 0) { nxt = sj; break; }
                    }
                    int cnt = nxt - s;
                    cf = (cnt < 1) ? 1.f : (float)cnt;
                }
                float acc2 = bc[c];
                for (int d = 0; d < DH; ++d) {
                    float hg = gsum[b * 128 + d] / cf + (nonempty ? b2[d] : 0.f);
                    acc2 += hg * Wc[d * NCLS + c];
                }
                for (int p = 0; p < PFEAT; ++p)
                    acc2 += perm[b * PFEAT + p] * Wc[(DH + p) * NCLS + c];
                fout[tid] = acc2;
            }
        }
    }
}

extern "C" void kernel_launch(void* const* d_in, const int* in_sizes, int n_in,
                              void* d_out, int out_size, void* d_ws, size_t ws_size,
                              hipStream_t stream) {
    const float* h    = (const float*)d_in[0];
    const int*   src  = (const int*)d_in[1];
    const int*   dst  = (const int*)d_in[2];
    const int*   gid  = (const int*)d_in[3];
    const float* perm = (const float*)d_in[4];
    const float* W1   = (const float*)d_in[5];
    const float* b1   = (const float*)d_in[6];
    const float* W2   = (const float*)d_in[7];
    const float* b2   = (const float*)d_in[8];
    const float* Wc   = (const float*)d_in[9];
    const float* bc   = (const float*)d_in[10];
    float* out = (float*)d_out;

    char* ws = (char*)d_ws;
    size_t off = 0;
    auto alloc = [&](size_t bytes) {
        void* p = ws + off;
        off = (off + bytes + 255) & ~(size_t)255;
        return p;
    };
    int*   deg     = (int*)alloc(N_NODES * 4);
    int*   row_ptr = (int*)alloc((N_NODES + 1) * 4);
    int*   col     = (int*)alloc(N_EDGES * 4);
    int*   epos    = (int*)alloc(N_EDGES * 4);
    int*   bsum    = (int*)alloc(SCAN_BLOCKS * 4);
    float* norm    = (float*)alloc(N_NODES * 4);
    unsigned short* h_bf = (unsigned short*)alloc((size_t)NPAD * 128 * 2);
    unsigned short* f1   = (unsigned short*)alloc((size_t)NPAD * 128 * 2);
    unsigned short* f2   = (unsigned short*)alloc((size_t)NPAD * 128 * 2);
    unsigned short* x2   = (unsigned short*)alloc((size_t)NPAD * 128 * 2);
    unsigned short* Wt1  = (unsigned short*)alloc(384 * 128 * 2);
    unsigned short* Wt2  = (unsigned short*)alloc(384 * 128 * 2);
    float* gsum    = (float*)alloc(B_GRAPHS * 128 * 4);
    int*   gstart  = (int*)alloc(B_GRAPHS * 4);
    int*   done    = (int*)alloc(4);

    // one fused init dispatch: zeroing + h->bf16 + W transposes
    k_init<<<(NCVT4 + 255) / 256, 256, 0, stream>>>(h, h_bf, W1, W2, Wt1, Wt2,
                                                    deg, gsum, gstart, done);
    // CSR build: deg+positions -> norm+bsum -> scan -> scatter (atomic-free)
    k_deg_bound<<<(N_EDGES + N_NODES + 255) / 256, 256, 0, stream>>>(dst, gid, deg, epos, gstart);
    k_norm_bsum<<<SCAN_BLOCKS, 256, 0, stream>>>(deg, norm, bsum);
    k_scan2<<<SCAN_BLOCKS, 256, 0, stream>>>(deg, bsum, row_ptr);
    k_scatter<<<(N_EDGES + 255) / 256, 256, 0, stream>>>(src, dst, row_ptr, epos, col);

    int spmm_grid = (N_NODES + 3) / 4;

    // Layer 1: feats = [h, f1, f2] -> x2 (relu, bf16)
    k_spmm<<<spmm_grid, 256, 0, stream>>>(h_bf, norm, row_ptr, col, f1);
    k_spmm<<<spmm_grid, 256, 0, stream>>>(f1, norm, row_ptr, col, f2);
    k_gemm_mfma<true, false><<<GEMM_GRID, 256, 0, stream>>>(
        h_bf, f1, f2, Wt1, b1, x2, gid, gsum, done,
        nullptr, nullptr, nullptr, nullptr, nullptr, nullptr);

    // Layer 2: feats = [x2, f1, f2] -> fused mean-pool + last-block final
    k_spmm<<<spmm_grid, 256, 0, stream>>>(x2, norm, row_ptr, col, f1);
    k_spmm<<<spmm_grid, 256, 0, stream>>>(f1, norm, row_ptr, col, f2);
    k_gemm_mfma<false, true><<<GEMM_GRID, 256, 0, stream>>>(
        x2, f1, f2, Wt2, nullptr, nullptr, gid, gsum, done,
        gstart, b2, perm, Wc, bc, out);
}

// Round 9
// 284.103 us; speedup vs baseline: 1.1702x; 1.1702x over previous
//
#include <hip/hip_runtime.h>

#define N_NODES 50000
#define N_EDGES 600000
#define B_GRAPHS 64
#define DH 128
#define PFEAT 32
#define NCLS 2
#define SCAN_BLOCKS ((N_NODES + 255) / 256)   // 196
#define NPAD (N_NODES + 128)                  // row padding for OOB-safe MFMA loads
#define NCVT4 (N_NODES * 128 / 4)             // 1,600,000
#define WELEMS (384 * 128)                    // 49,152
#define GEMM_GRID ((N_NODES + 63) / 64)       // 782

typedef __attribute__((ext_vector_type(8))) short short8v;
typedef __attribute__((ext_vector_type(4))) float float4v;
typedef __attribute__((ext_vector_type(4))) unsigned int uint4v;

__device__ __forceinline__ unsigned int f2bf(float f) {
    unsigned int u = __float_as_uint(f);
    return (u + 0x7FFFu + ((u >> 16) & 1u)) >> 16;   // RNE
}
__device__ __forceinline__ float bflo(unsigned int p) { return __uint_as_float(p << 16); }
__device__ __forceinline__ float bfhi(unsigned int p) { return __uint_as_float(p & 0xFFFF0000u); }

// ---------- fused init: zero scratch + h->bf16 + W1/W2 transpose-convert ----------
__global__ void k_init(const float* __restrict__ h, unsigned short* __restrict__ h_bf,
                       const float* __restrict__ W1, const float* __restrict__ W2,
                       unsigned short* __restrict__ Wt1, unsigned short* __restrict__ Wt2,
                       int* __restrict__ deg, float* __restrict__ gsum,
                       int* __restrict__ gstart) {
    int t = blockIdx.x * 256 + threadIdx.x;
    if (t < NCVT4) {
        float4 v = ((const float4*)h)[t];
        unsigned int lo = f2bf(v.x) | (f2bf(v.y) << 16);
        unsigned int hi = f2bf(v.z) | (f2bf(v.w) << 16);
        uint2 r; r.x = lo; r.y = hi;
        ((uint2*)h_bf)[t] = r;
    }
    if (t < 2 * WELEMS) {
        bool second = (t >= WELEMS);
        int idx = second ? t - WELEMS : t;
        const float* W = second ? W2 : W1;
        unsigned short* Wt = second ? Wt2 : Wt1;
        int k = idx >> 7, c = idx & 127;
        Wt[c * 384 + k] = (unsigned short)f2bf(W[idx]);
    }
    if (t < N_NODES) deg[t] = 0;
    if (t < B_GRAPHS * DH) gsum[t] = 0.f;
    if (t < B_GRAPHS) gstart[t] = -1;
}

// ---------- fused: degree atomics (saving bucket positions) + graph run-starts ----------
__global__ void k_deg_bound(const int* __restrict__ dst, const int* __restrict__ gid,
                            int* __restrict__ deg, int* __restrict__ epos,
                            int* __restrict__ gstart) {
    int t = blockIdx.x * 256 + threadIdx.x;
    if (t < N_EDGES) {
        int pos = atomicAdd(&deg[dst[t]], 1);
        epos[t] = pos;
    }
    int n = t - N_EDGES;
    if (n >= 0 && n < N_NODES) {
        int g = gid[n];
        if (n == 0 || gid[n - 1] != g) gstart[g] = n;
    }
}

// ---------- fused: norm + per-block degree sums ----------
__global__ void k_norm_bsum(const int* __restrict__ deg, float* __restrict__ norm,
                            int* __restrict__ bsum) {
    __shared__ int s[256];
    int i = blockIdx.x * 256 + threadIdx.x;
    int d = (i < N_NODES) ? deg[i] : 0;
    if (i < N_NODES) norm[i] = rsqrtf((float)(d < 1 ? 1 : d));
    s[threadIdx.x] = d;
    __syncthreads();
    for (int off = 128; off > 0; off >>= 1) {
        if (threadIdx.x < off) s[threadIdx.x] += s[threadIdx.x + off];
        __syncthreads();
    }
    if (threadIdx.x == 0) bsum[blockIdx.x] = s[0];
}

// ---------- scan: each block redundantly scans 196 block-sums in LDS + local scan ----------
__global__ void k_scan2(const int* __restrict__ deg, const int* __restrict__ bsum,
                        int* __restrict__ row_ptr) {
    __shared__ int sb[256];
    __shared__ int s[256];
    int bv = (threadIdx.x < SCAN_BLOCKS) ? bsum[threadIdx.x] : 0;
    sb[threadIdx.x] = bv;
    int i = blockIdx.x * 256 + threadIdx.x;
    int v = (i < N_NODES) ? deg[i] : 0;
    s[threadIdx.x] = v;
    __syncthreads();
    for (int off = 1; off < 256; off <<= 1) {
        int tb = (threadIdx.x >= off) ? sb[threadIdx.x - off] : 0;
        int t = (threadIdx.x >= off) ? s[threadIdx.x - off] : 0;
        __syncthreads();
        sb[threadIdx.x] += tb;
        s[threadIdx.x] += t;
        __syncthreads();
    }
    int block_off = (blockIdx.x == 0) ? 0 : sb[blockIdx.x - 1];
    if (i < N_NODES) row_ptr[i + 1] = s[threadIdx.x] + block_off;
    if (i == 0) row_ptr[0] = 0;
}

// ---------- scatter edges into CSR buckets (no atomics: positions precomputed) ----------
__global__ void k_scatter(const int* __restrict__ src, const int* __restrict__ dst,
                          const int* __restrict__ row_ptr, const int* __restrict__ epos,
                          int* __restrict__ col) {
    int e = blockIdx.x * blockDim.x + threadIdx.x;
    if (e < N_EDGES) {
        int d = dst[e];
        col[row_ptr[d] + epos[e]] = src[e];
    }
}

// ---------- SpMM hop (bf16 in/out, fp32 accumulate) ----------
__global__ __launch_bounds__(256) void k_spmm(const unsigned short* __restrict__ fin,
                                              const float* __restrict__ norm,
                                              const int* __restrict__ row_ptr,
                                              const int* __restrict__ col,
                                              unsigned short* __restrict__ fout) {
    int wave = threadIdx.x >> 6;
    int lane = threadIdx.x & 63;
    int grp = lane >> 4;
    int l15 = lane & 15;
    int v = blockIdx.x * 4 + wave;
    if (v >= N_NODES) return;
    int beg = row_ptr[v], end = row_ptr[v + 1];

    float a0[8], a1[8], a2[8], a3[8];
#pragma unroll
    for (int j = 0; j < 8; ++j) { a0[j] = 0.f; a1[j] = 0.f; a2[j] = 0.f; a3[j] = 0.f; }

    for (int base = beg; base < end; base += 16) {
        int e0 = base + grp;
        int e1 = e0 + 4, e2 = e0 + 8, e3 = e0 + 12;
        int last = end - 1;
        int c0 = (e0 < end) ? e0 : last;
        int c1 = (e1 < end) ? e1 : last;
        int c2 = (e2 < end) ? e2 : last;
        int c3 = (e3 < end) ? e3 : last;
        int u0 = col[c0], u1 = col[c1], u2 = col[c2], u3 = col[c3];
        uint4v r0 = *(const uint4v*)(fin + (size_t)u0 * 128 + l15 * 8);
        uint4v r1 = *(const uint4v*)(fin + (size_t)u1 * 128 + l15 * 8);
        uint4v r2 = *(const uint4v*)(fin + (size_t)u2 * 128 + l15 * 8);
        uint4v r3 = *(const uint4v*)(fin + (size_t)u3 * 128 + l15 * 8);
        float w0 = (e0 < end) ? norm[u0] : 0.f;
        float w1 = (e1 < end) ? norm[u1] : 0.f;
        float w2 = (e2 < end) ? norm[u2] : 0.f;
        float w3 = (e3 < end) ? norm[u3] : 0.f;
#pragma unroll
        for (int q = 0; q < 4; ++q) {
            a0[2 * q]     = fmaf(bflo(r0[q]), w0, a0[2 * q]);
            a0[2 * q + 1] = fmaf(bfhi(r0[q]), w0, a0[2 * q + 1]);
            a1[2 * q]     = fmaf(bflo(r1[q]), w1, a1[2 * q]);
            a1[2 * q + 1] = fmaf(bfhi(r1[q]), w1, a1[2 * q + 1]);
            a2[2 * q]     = fmaf(bflo(r2[q]), w2, a2[2 * q]);
            a2[2 * q + 1] = fmaf(bfhi(r2[q]), w2, a2[2 * q + 1]);
            a3[2 * q]     = fmaf(bflo(r3[q]), w3, a3[2 * q]);
            a3[2 * q + 1] = fmaf(bfhi(r3[q]), w3, a3[2 * q + 1]);
        }
    }

#pragma unroll
    for (int j = 0; j < 8; ++j) {
        float s = (a0[j] + a1[j]) + (a2[j] + a3[j]);
        s += __shfl_xor(s, 16, 64);
        s += __shfl_xor(s, 32, 64);
        a0[j] = s;
    }
    if (grp == 0) {
        float nv = norm[v];
        uint4v o;
#pragma unroll
        for (int q = 0; q < 4; ++q)
            o[q] = f2bf(a0[2 * q] * nv) | (f2bf(a0[2 * q + 1] * nv) << 16);
        *(uint4v*)(fout + (size_t)v * 128 + l15 * 8) = o;
    }
}

// ---------- bf16 MFMA GEMM: wave = 16 rows x 128 cols. Block = 4 waves = 64 rows ----------
template <bool RELU, bool POOL>
__global__ __launch_bounds__(256) void k_gemm_mfma(const unsigned short* __restrict__ A0,
                                                   const unsigned short* __restrict__ A1,
                                                   const unsigned short* __restrict__ A2,
                                                   const unsigned short* __restrict__ Wt,
                                                   const float* __restrict__ bias,
                                                   unsigned short* __restrict__ out,
                                                   const int* __restrict__ gid,
                                                   float* __restrict__ gsum) {
    __shared__ float red4[4][128];
    int tid = threadIdx.x;
    int lane = tid & 63;
    int wid = tid >> 6;
    int l15 = lane & 15;
    int lk = lane >> 4;                 // 0..3
    int n0 = blockIdx.x * 64;
    int rbase = n0 + wid * 16;

    float4v acc[8];
#pragma unroll
    for (int ct = 0; ct < 8; ++ct)
#pragma unroll
        for (int i = 0; i < 4; ++i) acc[ct][i] = 0.f;

    const unsigned short* Aseg[3] = {A0, A1, A2};
#pragma unroll
    for (int ks = 0; ks < 12; ++ks) {
        const unsigned short* A = Aseg[ks >> 2];
        int kloc = (ks & 3) * 32 + lk * 8;
        short8v a = *(const short8v*)(A + (size_t)(rbase + l15) * 128 + kloc);
        const unsigned short* wp = Wt + (size_t)l15 * 384 + ks * 32 + lk * 8;
#pragma unroll
        for (int ct = 0; ct < 8; ++ct) {
            short8v b = *(const short8v*)(wp + (size_t)ct * 16 * 384);
            acc[ct] = __builtin_amdgcn_mfma_f32_16x16x32_bf16(a, b, acc[ct], 0, 0, 0);
        }
    }

    if (!POOL) {
        // epilogue: + bias, relu, bf16 store. C/D: col=lane&15, row=(lane>>4)*4+i
        float bj[8];
#pragma unroll
        for (int ct = 0; ct < 8; ++ct) bj[ct] = bias[ct * 16 + l15];
#pragma unroll
        for (int i = 0; i < 4; ++i) {
            int row = rbase + lk * 4 + i;
            if (row < N_NODES) {
#pragma unroll
                for (int ct = 0; ct < 8; ++ct) {
                    float v = acc[ct][i] + bj[ct];
                    if (RELU) v = fmaxf(v, 0.f);
                    out[(size_t)row * 128 + ct * 16 + l15] = (unsigned short)f2bf(v);
                }
            }
        }
    } else {
        // fused mean-pool numerator (bias deferred to k_final)
        int gr[4];
#pragma unroll
        for (int i = 0; i < 4; ++i) {
            int row = rbase + lk * 4 + i;
            gr[i] = (row < N_NODES) ? gid[row] : -1;
        }
        int lastrow = n0 + 63;
        if (lastrow >= N_NODES) lastrow = N_NODES - 1;
        int gfirst = gid[n0];
        int glast = gid[lastrow];
        for (int g = gfirst; g <= glast; ++g) {
            float p[8];
#pragma unroll
            for (int ct = 0; ct < 8; ++ct) {
                float s = 0.f;
#pragma unroll
                for (int i = 0; i < 4; ++i)
                    if (gr[i] == g) s += acc[ct][i];
                p[ct] = s;
            }
#pragma unroll
            for (int ct = 0; ct < 8; ++ct) {
                p[ct] += __shfl_xor(p[ct], 16, 64);
                p[ct] += __shfl_xor(p[ct], 32, 64);
            }
            if (lane < 16) {
#pragma unroll
                for (int ct = 0; ct < 8; ++ct) red4[wid][ct * 16 + lane] = p[ct];
            }
            __syncthreads();
            if (tid < 128) {
                float s = red4[0][tid] + red4[1][tid] + red4[2][tid] + red4[3][tid];
                atomicAdd(&gsum[g * 128 + tid], s);
            }
            __syncthreads();
        }
    }
}

// ---------- final: counts from run-starts; combined = gsum/cnt + b2 ; out = @Wc + bc ----------
__global__ void k_final(const float* __restrict__ gsum, const int* __restrict__ gstart,
                        const float* __restrict__ b2, const float* __restrict__ perm,
                        const float* __restrict__ Wc, const float* __restrict__ bc,
                        float* __restrict__ out) {
    int t = threadIdx.x;
    if (t >= B_GRAPHS * NCLS) return;
    int b = t / NCLS, c = t % NCLS;
    int s = gstart[b];
    float cf = 1.f;
    bool nonempty = (s >= 0);
    if (nonempty) {
        int nxt = N_NODES;
        for (int j = b + 1; j < B_GRAPHS; ++j) {
            int sj = gstart[j];
            if (sj >= 0) { nxt = sj; break; }
        }
        int cnt = nxt - s;
        cf = (cnt < 1) ? 1.f : (float)cnt;
    }
    float acc = bc[c];
    for (int d = 0; d < DH; ++d) {
        float hg = gsum[b * 128 + d] / cf + (nonempty ? b2[d] : 0.f);
        acc += hg * Wc[d * NCLS + c];
    }
    for (int p = 0; p < PFEAT; ++p) acc += perm[b * PFEAT + p] * Wc[(DH + p) * NCLS + c];
    out[t] = acc;
}

extern "C" void kernel_launch(void* const* d_in, const int* in_sizes, int n_in,
                              void* d_out, int out_size, void* d_ws, size_t ws_size,
                              hipStream_t stream) {
    const float* h    = (const float*)d_in[0];
    const int*   src  = (const int*)d_in[1];
    const int*   dst  = (const int*)d_in[2];
    const int*   gid  = (const int*)d_in[3];
    const float* perm = (const float*)d_in[4];
    const float* W1   = (const float*)d_in[5];
    const float* b1   = (const float*)d_in[6];
    const float* W2   = (const float*)d_in[7];
    const float* b2   = (const float*)d_in[8];
    const float* Wc   = (const float*)d_in[9];
    const float* bc   = (const float*)d_in[10];
    float* out = (float*)d_out;

    char* ws = (char*)d_ws;
    size_t off = 0;
    auto alloc = [&](size_t bytes) {
        void* p = ws + off;
        off = (off + bytes + 255) & ~(size_t)255;
        return p;
    };
    int*   deg     = (int*)alloc(N_NODES * 4);
    int*   row_ptr = (int*)alloc((N_NODES + 1) * 4);
    int*   col     = (int*)alloc(N_EDGES * 4);
    int*   epos    = (int*)alloc(N_EDGES * 4);
    int*   bsum    = (int*)alloc(SCAN_BLOCKS * 4);
    float* norm    = (float*)alloc(N_NODES * 4);
    unsigned short* h_bf = (unsigned short*)alloc((size_t)NPAD * 128 * 2);
    unsigned short* f1   = (unsigned short*)alloc((size_t)NPAD * 128 * 2);
    unsigned short* f2   = (unsigned short*)alloc((size_t)NPAD * 128 * 2);
    unsigned short* x2   = (unsigned short*)alloc((size_t)NPAD * 128 * 2);
    unsigned short* Wt1  = (unsigned short*)alloc(384 * 128 * 2);
    unsigned short* Wt2  = (unsigned short*)alloc(384 * 128 * 2);
    float* gsum    = (float*)alloc(B_GRAPHS * 128 * 4);
    int*   gstart  = (int*)alloc(B_GRAPHS * 4);

    // one fused init dispatch: zeroing + h->bf16 + W transposes
    k_init<<<(NCVT4 + 255) / 256, 256, 0, stream>>>(h, h_bf, W1, W2, Wt1, Wt2,
                                                    deg, gsum, gstart);
    // CSR build: deg+positions -> norm+bsum -> scan -> scatter (atomic-free)
    k_deg_bound<<<(N_EDGES + N_NODES + 255) / 256, 256, 0, stream>>>(dst, gid, deg, epos, gstart);
    k_norm_bsum<<<SCAN_BLOCKS, 256, 0, stream>>>(deg, norm, bsum);
    k_scan2<<<SCAN_BLOCKS, 256, 0, stream>>>(deg, bsum, row_ptr);
    k_scatter<<<(N_EDGES + 255) / 256, 256, 0, stream>>>(src, dst, row_ptr, epos, col);

    int spmm_grid = (N_NODES + 3) / 4;

    // Layer 1: feats = [h, f1, f2] -> x2 (relu, bf16)
    k_spmm<<<spmm_grid, 256, 0, stream>>>(h_bf, norm, row_ptr, col, f1);
    k_spmm<<<spmm_grid, 256, 0, stream>>>(f1, norm, row_ptr, col, f2);
    k_gemm_mfma<true, false><<<GEMM_GRID, 256, 0, stream>>>(h_bf, f1, f2, Wt1, b1, x2, gid, gsum);

    // Layer 2: feats = [x2, f1, f2] -> fused mean-pool numerator
    k_spmm<<<spmm_grid, 256, 0, stream>>>(x2, norm, row_ptr, col, f1);
    k_spmm<<<spmm_grid, 256, 0, stream>>>(f1, norm, row_ptr, col, f2);
    k_gemm_mfma<false, true><<<GEMM_GRID, 256, 0, stream>>>(x2, f1, f2, Wt2, nullptr, nullptr, gid, gsum);

    // Readout
    k_final<<<1, 128, 0, stream>>>(gsum, gstart, b2, perm, Wc, bc, out);
}

// Round 10
// 248.160 us; speedup vs baseline: 1.3397x; 1.1448x over previous
//
#include <hip/hip_runtime.h>

#define N_NODES 50000
#define N_EDGES 600000
#define B_GRAPHS 64
#define DH 128
#define PFEAT 32
#define NCLS 2
#define SCAN_BLOCKS ((N_NODES + 255) / 256)   // 196
#define NPAD (N_NODES + 128)                  // row padding for OOB-safe MFMA loads
#define NCVT4 (N_NODES * 128 / 4)             // 1,600,000
#define WELEMS (384 * 128)                    // 49,152

typedef __attribute__((ext_vector_type(8))) short short8v;
typedef __attribute__((ext_vector_type(4))) float float4v;
typedef __attribute__((ext_vector_type(4))) unsigned int uint4v;

__device__ __forceinline__ unsigned int f2bf(float f) {
    unsigned int u = __float_as_uint(f);
    return (u + 0x7FFFu + ((u >> 16) & 1u)) >> 16;   // RNE
}
__device__ __forceinline__ float bflo(unsigned int p) { return __uint_as_float(p << 16); }
__device__ __forceinline__ float bfhi(unsigned int p) { return __uint_as_float(p & 0xFFFF0000u); }

// ---------- fused init: zero scratch + h->bf16 + W1/W2 transpose-convert ----------
__global__ void k_init(const float* __restrict__ h, unsigned short* __restrict__ h_bf,
                       const float* __restrict__ W1, const float* __restrict__ W2,
                       unsigned short* __restrict__ Wt1, unsigned short* __restrict__ Wt2,
                       int* __restrict__ deg, float* __restrict__ gsum,
                       int* __restrict__ gstart) {
    int t = blockIdx.x * 256 + threadIdx.x;
    if (t < NCVT4) {
        float4 v = ((const float4*)h)[t];
        unsigned int lo = f2bf(v.x) | (f2bf(v.y) << 16);
        unsigned int hi = f2bf(v.z) | (f2bf(v.w) << 16);
        uint2 r; r.x = lo; r.y = hi;
        ((uint2*)h_bf)[t] = r;
    }
    if (t < 2 * WELEMS) {
        bool second = (t >= WELEMS);
        int idx = second ? t - WELEMS : t;
        const float* W = second ? W2 : W1;
        unsigned short* Wt = second ? Wt2 : Wt1;
        int k = idx >> 7, c = idx & 127;
        Wt[c * 384 + k] = (unsigned short)f2bf(W[idx]);
    }
    if (t < N_NODES) deg[t] = 0;
    if (t < B_GRAPHS * DH) gsum[t] = 0.f;
    if (t < B_GRAPHS) gstart[t] = -1;
}

// ---------- fused: degree atomics (saving bucket positions) + graph run-starts ----------
__global__ void k_deg_bound(const int* __restrict__ dst, const int* __restrict__ gid,
                            int* __restrict__ deg, int* __restrict__ epos,
                            int* __restrict__ gstart) {
    int t = blockIdx.x * 256 + threadIdx.x;
    if (t < N_EDGES) {
        int pos = atomicAdd(&deg[dst[t]], 1);
        epos[t] = pos;
    }
    int n = t - N_EDGES;
    if (n >= 0 && n < N_NODES) {
        int g = gid[n];
        if (n == 0 || gid[n - 1] != g) gstart[g] = n;
    }
}

// ---------- fused: norm + per-block degree sums ----------
__global__ void k_norm_bsum(const int* __restrict__ deg, float* __restrict__ norm,
                            int* __restrict__ bsum) {
    __shared__ int s[256];
    int i = blockIdx.x * 256 + threadIdx.x;
    int d = (i < N_NODES) ? deg[i] : 0;
    if (i < N_NODES) norm[i] = rsqrtf((float)(d < 1 ? 1 : d));
    s[threadIdx.x] = d;
    __syncthreads();
    for (int off = 128; off > 0; off >>= 1) {
        if (threadIdx.x < off) s[threadIdx.x] += s[threadIdx.x + off];
        __syncthreads();
    }
    if (threadIdx.x == 0) bsum[blockIdx.x] = s[0];
}

// ---------- scan: each block redundantly scans 196 block-sums in LDS + local scan ----------
__global__ void k_scan2(const int* __restrict__ deg, const int* __restrict__ bsum,
                        int* __restrict__ row_ptr) {
    __shared__ int sb[256];
    __shared__ int s[256];
    int bv = (threadIdx.x < SCAN_BLOCKS) ? bsum[threadIdx.x] : 0;
    sb[threadIdx.x] = bv;
    int i = blockIdx.x * 256 + threadIdx.x;
    int v = (i < N_NODES) ? deg[i] : 0;
    s[threadIdx.x] = v;
    __syncthreads();
    for (int off = 1; off < 256; off <<= 1) {
        int tb = (threadIdx.x >= off) ? sb[threadIdx.x - off] : 0;
        int t = (threadIdx.x >= off) ? s[threadIdx.x - off] : 0;
        __syncthreads();
        sb[threadIdx.x] += tb;
        s[threadIdx.x] += t;
        __syncthreads();
    }
    int block_off = (blockIdx.x == 0) ? 0 : sb[blockIdx.x - 1];
    if (i < N_NODES) row_ptr[i + 1] = s[threadIdx.x] + block_off;
    if (i == 0) row_ptr[0] = 0;
}

// ---------- scatter edges into CSR buckets (no atomics: positions precomputed) ----------
__global__ void k_scatter(const int* __restrict__ src, const int* __restrict__ dst,
                          const int* __restrict__ row_ptr, const int* __restrict__ epos,
                          int* __restrict__ col) {
    int e = blockIdx.x * blockDim.x + threadIdx.x;
    if (e < N_EDGES) {
        int d = dst[e];
        col[row_ptr[d] + epos[e]] = src[e];
    }
}

// ---------- SpMM hop (bf16 in/out, fp32 accumulate) ----------
__global__ __launch_bounds__(256) void k_spmm(const unsigned short* __restrict__ fin,
                                              const float* __restrict__ norm,
                                              const int* __restrict__ row_ptr,
                                              const int* __restrict__ col,
                                              unsigned short* __restrict__ fout) {
    int wave = threadIdx.x >> 6;
    int lane = threadIdx.x & 63;
    int grp = lane >> 4;
    int l15 = lane & 15;
    int v = blockIdx.x * 4 + wave;
    if (v >= N_NODES) return;
    int beg = row_ptr[v], end = row_ptr[v + 1];

    float a0[8], a1[8], a2[8], a3[8];
#pragma unroll
    for (int j = 0; j < 8; ++j) { a0[j] = 0.f; a1[j] = 0.f; a2[j] = 0.f; a3[j] = 0.f; }

    for (int base = beg; base < end; base += 16) {
        int e0 = base + grp;
        int e1 = e0 + 4, e2 = e0 + 8, e3 = e0 + 12;
        int last = end - 1;
        int c0 = (e0 < end) ? e0 : last;
        int c1 = (e1 < end) ? e1 : last;
        int c2 = (e2 < end) ? e2 : last;
        int c3 = (e3 < end) ? e3 : last;
        int u0 = col[c0], u1 = col[c1], u2 = col[c2], u3 = col[c3];
        uint4v r0 = *(const uint4v*)(fin + (size_t)u0 * 128 + l15 * 8);
        uint4v r1 = *(const uint4v*)(fin + (size_t)u1 * 128 + l15 * 8);
        uint4v r2 = *(const uint4v*)(fin + (size_t)u2 * 128 + l15 * 8);
        uint4v r3 = *(const uint4v*)(fin + (size_t)u3 * 128 + l15 * 8);
        float w0 = (e0 < end) ? norm[u0] : 0.f;
        float w1 = (e1 < end) ? norm[u1] : 0.f;
        float w2 = (e2 < end) ? norm[u2] : 0.f;
        float w3 = (e3 < end) ? norm[u3] : 0.f;
#pragma unroll
        for (int q = 0; q < 4; ++q) {
            a0[2 * q]     = fmaf(bflo(r0[q]), w0, a0[2 * q]);
            a0[2 * q + 1] = fmaf(bfhi(r0[q]), w0, a0[2 * q + 1]);
            a1[2 * q]     = fmaf(bflo(r1[q]), w1, a1[2 * q]);
            a1[2 * q + 1] = fmaf(bfhi(r1[q]), w1, a1[2 * q + 1]);
            a2[2 * q]     = fmaf(bflo(r2[q]), w2, a2[2 * q]);
            a2[2 * q + 1] = fmaf(bfhi(r2[q]), w2, a2[2 * q + 1]);
            a3[2 * q]     = fmaf(bflo(r3[q]), w3, a3[2 * q]);
            a3[2 * q + 1] = fmaf(bfhi(r3[q]), w3, a3[2 * q + 1]);
        }
    }

#pragma unroll
    for (int j = 0; j < 8; ++j) {
        float s = (a0[j] + a1[j]) + (a2[j] + a3[j]);
        s += __shfl_xor(s, 16, 64);
        s += __shfl_xor(s, 32, 64);
        a0[j] = s;
    }
    if (grp == 0) {
        float nv = norm[v];
        uint4v o;
#pragma unroll
        for (int q = 0; q < 4; ++q)
            o[q] = f2bf(a0[2 * q] * nv) | (f2bf(a0[2 * q + 1] * nv) << 16);
        *(uint4v*)(fout + (size_t)v * 128 + l15 * 8) = o;
    }
}

// ---------- bf16 MFMA GEMM (round-6 geometry): wave = 32 rows x 128 cols ----------
// Block = 256 thr = 4 waves = 128 rows. grid = 391. 2 A-frags : 8 B-frags per k-step.
template <bool RELU, bool POOL>
__global__ __launch_bounds__(256) void k_gemm_mfma(const unsigned short* __restrict__ A0,
                                                   const unsigned short* __restrict__ A1,
                                                   const unsigned short* __restrict__ A2,
                                                   const unsigned short* __restrict__ Wt,
                                                   const float* __restrict__ bias,
                                                   unsigned short* __restrict__ out,
                                                   const int* __restrict__ gid,
                                                   float* __restrict__ gsum) {
    __shared__ float red4[4][128];
    int tid = threadIdx.x;
    int lane = tid & 63;
    int wid = tid >> 6;
    int l15 = lane & 15;
    int lk = lane >> 4;                 // 0..3
    int n0 = blockIdx.x * 128;
    int rbase = n0 + wid * 32;

    float4v acc[2][8];
#pragma unroll
    for (int rt = 0; rt < 2; ++rt)
#pragma unroll
        for (int ct = 0; ct < 8; ++ct)
#pragma unroll
            for (int i = 0; i < 4; ++i) acc[rt][ct][i] = 0.f;

    const unsigned short* Aseg[3] = {A0, A1, A2};
#pragma unroll
    for (int ks = 0; ks < 12; ++ks) {
        const unsigned short* A = Aseg[ks >> 2];
        int kloc = (ks & 3) * 32 + lk * 8;
        short8v a0 = *(const short8v*)(A + (size_t)(rbase + l15) * 128 + kloc);
        short8v a1 = *(const short8v*)(A + (size_t)(rbase + 16 + l15) * 128 + kloc);
        const unsigned short* wp = Wt + (size_t)l15 * 384 + ks * 32 + lk * 8;
#pragma unroll
        for (int ct = 0; ct < 8; ++ct) {
            short8v b = *(const short8v*)(wp + (size_t)ct * 16 * 384);
            acc[0][ct] = __builtin_amdgcn_mfma_f32_16x16x32_bf16(a0, b, acc[0][ct], 0, 0, 0);
            acc[1][ct] = __builtin_amdgcn_mfma_f32_16x16x32_bf16(a1, b, acc[1][ct], 0, 0, 0);
        }
    }

    if (!POOL) {
        // epilogue: + bias, relu, bf16 store. C/D: col=lane&15, row=(lane>>4)*4+reg
        float bj[8];
#pragma unroll
        for (int ct = 0; ct < 8; ++ct) bj[ct] = bias[ct * 16 + l15];
#pragma unroll
        for (int rt = 0; rt < 2; ++rt)
#pragma unroll
            for (int i = 0; i < 4; ++i) {
                int row = rbase + rt * 16 + lk * 4 + i;
                if (row < N_NODES) {
#pragma unroll
                    for (int ct = 0; ct < 8; ++ct) {
                        float v = acc[rt][ct][i] + bj[ct];
                        if (RELU) v = fmaxf(v, 0.f);
                        out[(size_t)row * 128 + ct * 16 + l15] = (unsigned short)f2bf(v);
                    }
                }
            }
    } else {
        // fused mean-pool numerator (bias deferred to k_final)
        int gr[2][4];
#pragma unroll
        for (int rt = 0; rt < 2; ++rt)
#pragma unroll
            for (int i = 0; i < 4; ++i) {
                int row = rbase + rt * 16 + lk * 4 + i;
                gr[rt][i] = (row < N_NODES) ? gid[row] : -1;
            }
        int lastrow = n0 + 127;
        if (lastrow >= N_NODES) lastrow = N_NODES - 1;
        int gfirst = gid[n0];
        int glast = gid[lastrow];
        for (int g = gfirst; g <= glast; ++g) {
            float p[8];
#pragma unroll
            for (int ct = 0; ct < 8; ++ct) {
                float s = 0.f;
#pragma unroll
                for (int rt = 0; rt < 2; ++rt)
#pragma unroll
                    for (int i = 0; i < 4; ++i)
                        if (gr[rt][i] == g) s += acc[rt][ct][i];
                p[ct] = s;
            }
#pragma unroll
            for (int ct = 0; ct < 8; ++ct) {
                p[ct] += __shfl_xor(p[ct], 16, 64);
                p[ct] += __shfl_xor(p[ct], 32, 64);
            }
            if (lane < 16) {
#pragma unroll
                for (int ct = 0; ct < 8; ++ct) red4[wid][ct * 16 + lane] = p[ct];
            }
            __syncthreads();
            if (tid < 128) {
                float s = red4[0][tid] + red4[1][tid] + red4[2][tid] + red4[3][tid];
                atomicAdd(&gsum[g * 128 + tid], s);
            }
            __syncthreads();
        }
    }
}

// ---------- final: counts from run-starts; combined = gsum/cnt + b2 ; out = @Wc + bc ----------
__global__ void k_final(const float* __restrict__ gsum, const int* __restrict__ gstart,
                        const float* __restrict__ b2, const float* __restrict__ perm,
                        const float* __restrict__ Wc, const float* __restrict__ bc,
                        float* __restrict__ out) {
    int t = threadIdx.x;
    if (t >= B_GRAPHS * NCLS) return;
    int b = t / NCLS, c = t % NCLS;
    int s = gstart[b];
    float cf = 1.f;
    bool nonempty = (s >= 0);
    if (nonempty) {
        int nxt = N_NODES;
        for (int j = b + 1; j < B_GRAPHS; ++j) {
            int sj = gstart[j];
            if (sj >= 0) { nxt = sj; break; }
        }
        int cnt = nxt - s;
        cf = (cnt < 1) ? 1.f : (float)cnt;
    }
    float acc = bc[c];
    for (int d = 0; d < DH; ++d) {
        float hg = gsum[b * 128 + d] / cf + (nonempty ? b2[d] : 0.f);
        acc += hg * Wc[d * NCLS + c];
    }
    for (int p = 0; p < PFEAT; ++p) acc += perm[b * PFEAT + p] * Wc[(DH + p) * NCLS + c];
    out[t] = acc;
}

extern "C" void kernel_launch(void* const* d_in, const int* in_sizes, int n_in,
                              void* d_out, int out_size, void* d_ws, size_t ws_size,
                              hipStream_t stream) {
    const float* h    = (const float*)d_in[0];
    const int*   src  = (const int*)d_in[1];
    const int*   dst  = (const int*)d_in[2];
    const int*   gid  = (const int*)d_in[3];
    const float* perm = (const float*)d_in[4];
    const float* W1   = (const float*)d_in[5];
    const float* b1   = (const float*)d_in[6];
    const float* W2   = (const float*)d_in[7];
    const float* b2   = (const float*)d_in[8];
    const float* Wc   = (const float*)d_in[9];
    const float* bc   = (const float*)d_in[10];
    float* out = (float*)d_out;

    char* ws = (char*)d_ws;
    size_t off = 0;
    auto alloc = [&](size_t bytes) {
        void* p = ws + off;
        off = (off + bytes + 255) & ~(size_t)255;
        return p;
    };
    int*   deg     = (int*)alloc(N_NODES * 4);
    int*   row_ptr = (int*)alloc((N_NODES + 1) * 4);
    int*   col     = (int*)alloc(N_EDGES * 4);
    int*   epos    = (int*)alloc(N_EDGES * 4);
    int*   bsum    = (int*)alloc(SCAN_BLOCKS * 4);
    float* norm    = (float*)alloc(N_NODES * 4);
    unsigned short* h_bf = (unsigned short*)alloc((size_t)NPAD * 128 * 2);
    unsigned short* f1   = (unsigned short*)alloc((size_t)NPAD * 128 * 2);
    unsigned short* f2   = (unsigned short*)alloc((size_t)NPAD * 128 * 2);
    unsigned short* x2   = (unsigned short*)alloc((size_t)NPAD * 128 * 2);
    unsigned short* Wt1  = (unsigned short*)alloc(384 * 128 * 2);
    unsigned short* Wt2  = (unsigned short*)alloc(384 * 128 * 2);
    float* gsum    = (float*)alloc(B_GRAPHS * 128 * 4);
    int*   gstart  = (int*)alloc(B_GRAPHS * 4);

    // one fused init dispatch: zeroing + h->bf16 + W transposes
    k_init<<<(NCVT4 + 255) / 256, 256, 0, stream>>>(h, h_bf, W1, W2, Wt1, Wt2,
                                                    deg, gsum, gstart);
    // CSR build: deg+positions -> norm+bsum -> scan -> scatter (atomic-free)
    k_deg_bound<<<(N_EDGES + N_NODES + 255) / 256, 256, 0, stream>>>(dst, gid, deg, epos, gstart);
    k_norm_bsum<<<SCAN_BLOCKS, 256, 0, stream>>>(deg, norm, bsum);
    k_scan2<<<SCAN_BLOCKS, 256, 0, stream>>>(deg, bsum, row_ptr);
    k_scatter<<<(N_EDGES + 255) / 256, 256, 0, stream>>>(src, dst, row_ptr, epos, col);

    int spmm_grid = (N_NODES + 3) / 4;
    int gemm_grid = (N_NODES + 127) / 128;

    // Layer 1: feats = [h, f1, f2] -> x2 (relu, bf16)
    k_spmm<<<spmm_grid, 256, 0, stream>>>(h_bf, norm, row_ptr, col, f1);
    k_spmm<<<spmm_grid, 256, 0, stream>>>(f1, norm, row_ptr, col, f2);
    k_gemm_mfma<true, false><<<gemm_grid, 256, 0, stream>>>(h_bf, f1, f2, Wt1, b1, x2, gid, gsum);

    // Layer 2: feats = [x2, f1, f2] -> fused mean-pool numerator
    k_spmm<<<spmm_grid, 256, 0, stream>>>(x2, norm, row_ptr, col, f1);
    k_spmm<<<spmm_grid, 256, 0, stream>>>(f1, norm, row_ptr, col, f2);
    k_gemm_mfma<false, true><<<gemm_grid, 256, 0, stream>>>(x2, f1, f2, Wt2, nullptr, nullptr, gid, gsum);

    // Readout
    k_final<<<1, 128, 0, stream>>>(gsum, gstart, b2, perm, Wc, bc, out);
}

// Round 11
// 244.072 us; speedup vs baseline: 1.3621x; 1.0167x over previous
//
#include <hip/hip_runtime.h>

#define N_NODES 50000
#define N_EDGES 600000
#define B_GRAPHS 64
#define DH 128
#define PFEAT 32
#define NCLS 2
#define SCAN_BLOCKS ((N_NODES + 255) / 256)   // 196
#define NPAD (N_NODES + 128)                  // row padding (row N_NODES = zero row)
#define NCVT4 (N_NODES * 128 / 4)             // 1,600,000 float4 chunks
#define WELEMS (384 * 128)                    // 49,152

typedef __attribute__((ext_vector_type(8))) short short8v;
typedef __attribute__((ext_vector_type(4))) float float4v;
typedef __attribute__((ext_vector_type(4))) unsigned int uint4v;

__device__ __forceinline__ unsigned int f2bf(float f) {
    unsigned int u = __float_as_uint(f);
    return (u + 0x7FFFu + ((u >> 16) & 1u)) >> 16;   // RNE
}
__device__ __forceinline__ float bflo(unsigned int p) { return __uint_as_float(p << 16); }
__device__ __forceinline__ float bfhi(unsigned int p) { return __uint_as_float(p & 0xFFFF0000u); }

// ---------- init: zero scratch + W1/W2 transpose-convert + zero pad rows ----------
__global__ void k_init(const float* __restrict__ W1, const float* __restrict__ W2,
                       unsigned short* __restrict__ Wt1, unsigned short* __restrict__ Wt2,
                       int* __restrict__ deg, float* __restrict__ gsum,
                       int* __restrict__ gstart,
                       unsigned short* __restrict__ h_bf, unsigned short* __restrict__ f1,
                       unsigned short* __restrict__ f2, unsigned short* __restrict__ x2) {
    int t = blockIdx.x * 256 + threadIdx.x;
    if (t < 2 * WELEMS) {
        bool second = (t >= WELEMS);
        int idx = second ? t - WELEMS : t;
        const float* W = second ? W2 : W1;
        unsigned short* Wt = second ? Wt2 : Wt1;
        int k = idx >> 7, c = idx & 127;
        Wt[c * 384 + k] = (unsigned short)f2bf(W[idx]);
    }
    if (t < N_NODES) deg[t] = 0;
    if (t < B_GRAPHS * DH) gsum[t] = 0.f;
    if (t < B_GRAPHS) gstart[t] = -1;
    if (t < 4 * 32) {  // zero row N_NODES of each feature buffer (clamp target)
        unsigned short* bufs[4] = {h_bf, f1, f2, x2};
        uint2 z; z.x = 0u; z.y = 0u;
        ((uint2*)(bufs[t >> 5] + (size_t)N_NODES * 128))[t & 31] = z;
    }
}

// ---------- fused: degree atomics (saving bucket positions) + graph run-starts ----------
__global__ void k_deg_bound(const int* __restrict__ dst, const int* __restrict__ gid,
                            int* __restrict__ deg, int* __restrict__ epos,
                            int* __restrict__ gstart) {
    int t = blockIdx.x * 256 + threadIdx.x;
    if (t < N_EDGES) {
        int pos = atomicAdd(&deg[dst[t]], 1);
        epos[t] = pos;
    }
    int n = t - N_EDGES;
    if (n >= 0 && n < N_NODES) {
        int g = gid[n];
        if (n == 0 || gid[n - 1] != g) gstart[g] = n;
    }
}

// ---------- fused: norm + rnorm + per-block degree sums ----------
__global__ void k_norm_bsum(const int* __restrict__ deg, float* __restrict__ norm,
                            float* __restrict__ rnorm, int* __restrict__ bsum) {
    __shared__ int s[256];
    int i = blockIdx.x * 256 + threadIdx.x;
    int d = (i < N_NODES) ? deg[i] : 0;
    if (i < N_NODES) {
        int dc = d < 1 ? 1 : d;
        norm[i] = rsqrtf((float)dc);
        rnorm[i] = sqrtf((float)dc);
    }
    s[threadIdx.x] = d;
    __syncthreads();
    for (int off = 128; off > 0; off >>= 1) {
        if (threadIdx.x < off) s[threadIdx.x] += s[threadIdx.x + off];
        __syncthreads();
    }
    if (threadIdx.x == 0) bsum[blockIdx.x] = s[0];
}

// ---------- scan: each block redundantly scans 196 block-sums in LDS + local scan ----------
__global__ void k_scan2(const int* __restrict__ deg, const int* __restrict__ bsum,
                        int* __restrict__ row_ptr) {
    __shared__ int sb[256];
    __shared__ int s[256];
    int bv = (threadIdx.x < SCAN_BLOCKS) ? bsum[threadIdx.x] : 0;
    sb[threadIdx.x] = bv;
    int i = blockIdx.x * 256 + threadIdx.x;
    int v = (i < N_NODES) ? deg[i] : 0;
    s[threadIdx.x] = v;
    __syncthreads();
    for (int off = 1; off < 256; off <<= 1) {
        int tb = (threadIdx.x >= off) ? sb[threadIdx.x - off] : 0;
        int t = (threadIdx.x >= off) ? s[threadIdx.x - off] : 0;
        __syncthreads();
        sb[threadIdx.x] += tb;
        s[threadIdx.x] += t;
        __syncthreads();
    }
    int block_off = (blockIdx.x == 0) ? 0 : sb[blockIdx.x - 1];
    if (i < N_NODES) row_ptr[i + 1] = s[threadIdx.x] + block_off;
    if (i == 0) row_ptr[0] = 0;
}

// ---------- fused: atomic-free scatter + h -> bf16 pre-scaled by norm ----------
__global__ void k_scatter_cvt(const int* __restrict__ src, const int* __restrict__ dst,
                              const int* __restrict__ row_ptr, const int* __restrict__ epos,
                              int* __restrict__ col, const float* __restrict__ h,
                              const float* __restrict__ norm,
                              unsigned short* __restrict__ h_bf) {
    int t = blockIdx.x * 256 + threadIdx.x;
    if (t < N_EDGES) {
        int d = dst[t];
        col[row_ptr[d] + epos[t]] = src[t];
    }
    if (t < NCVT4) {
        float4 v = ((const float4*)h)[t];
        float nv = norm[t >> 5];                 // 32 float4 chunks per 128-wide row
        unsigned int lo = f2bf(v.x * nv) | (f2bf(v.y * nv) << 16);
        unsigned int hi = f2bf(v.z * nv) | (f2bf(v.w * nv) << 16);
        uint2 r; r.x = lo; r.y = hi;
        ((uint2*)h_bf)[t] = r;
    }
}

// ---------- SpMM hop on pre-scaled features: y_out[v] = norm[v]^2 * sum y_in[u] ----------
// Wave = 4 groups x 16 lanes; 4-deep edge pipeline; OOB slots gather the zero pad row.
__global__ __launch_bounds__(256) void k_spmm(const unsigned short* __restrict__ fin,
                                              const float* __restrict__ norm,
                                              const int* __restrict__ row_ptr,
                                              const int* __restrict__ col,
                                              unsigned short* __restrict__ fout) {
    int wave = threadIdx.x >> 6;
    int lane = threadIdx.x & 63;
    int grp = lane >> 4;
    int l15 = lane & 15;
    int v = blockIdx.x * 4 + wave;
    if (v >= N_NODES) return;
    int beg = row_ptr[v], end = row_ptr[v + 1];

    float a0[8], a1[8], a2[8], a3[8];
#pragma unroll
    for (int j = 0; j < 8; ++j) { a0[j] = 0.f; a1[j] = 0.f; a2[j] = 0.f; a3[j] = 0.f; }

    for (int base = beg; base < end; base += 16) {
        int e0 = base + grp;
        int e1 = e0 + 4, e2 = e0 + 8, e3 = e0 + 12;
        int last = end - 1;
        int c0 = (e0 < end) ? e0 : last;
        int c1 = (e1 < end) ? e1 : last;
        int c2 = (e2 < end) ? e2 : last;
        int c3 = (e3 < end) ? e3 : last;
        int u0 = col[c0], u1 = col[c1], u2 = col[c2], u3 = col[c3];
        // OOB slots -> zero pad row (adds 0, no weight needed)
        u0 = (e0 < end) ? u0 : N_NODES;
        u1 = (e1 < end) ? u1 : N_NODES;
        u2 = (e2 < end) ? u2 : N_NODES;
        u3 = (e3 < end) ? u3 : N_NODES;
        uint4v r0 = *(const uint4v*)(fin + (size_t)u0 * 128 + l15 * 8);
        uint4v r1 = *(const uint4v*)(fin + (size_t)u1 * 128 + l15 * 8);
        uint4v r2 = *(const uint4v*)(fin + (size_t)u2 * 128 + l15 * 8);
        uint4v r3 = *(const uint4v*)(fin + (size_t)u3 * 128 + l15 * 8);
#pragma unroll
        for (int q = 0; q < 4; ++q) {
            a0[2 * q]     += bflo(r0[q]);
            a0[2 * q + 1] += bfhi(r0[q]);
            a1[2 * q]     += bflo(r1[q]);
            a1[2 * q + 1] += bfhi(r1[q]);
            a2[2 * q]     += bflo(r2[q]);
            a2[2 * q + 1] += bfhi(r2[q]);
            a3[2 * q]     += bflo(r3[q]);
            a3[2 * q + 1] += bfhi(r3[q]);
        }
    }

#pragma unroll
    for (int j = 0; j < 8; ++j) {
        float s = (a0[j] + a1[j]) + (a2[j] + a3[j]);
        s += __shfl_xor(s, 16, 64);
        s += __shfl_xor(s, 32, 64);
        a0[j] = s;
    }
    if (grp == 0) {
        float nv = norm[v];
        float s2 = nv * nv;
        uint4v o;
#pragma unroll
        for (int q = 0; q < 4; ++q)
            o[q] = f2bf(a0[2 * q] * s2) | (f2bf(a0[2 * q + 1] * s2) << 16);
        *(uint4v*)(fout + (size_t)v * 128 + l15 * 8) = o;
    }
}

// ---------- bf16 MFMA GEMM on scaled features: wave = 32 rows x 128 cols ----------
// acc_row = norm[row] * ([x|Ax|A2x]@W)_row.
// RELU path:  write norm*relu(unscaled+b) = relu(acc + norm*b)  (rescaled for next layer)
// POOL path:  pool rnorm[row]*acc (unscaled), bias deferred to k_final
template <bool RELU, bool POOL>
__global__ __launch_bounds__(256) void k_gemm_mfma(const unsigned short* __restrict__ A0,
                                                   const unsigned short* __restrict__ A1,
                                                   const unsigned short* __restrict__ A2,
                                                   const unsigned short* __restrict__ Wt,
                                                   const float* __restrict__ bias,
                                                   unsigned short* __restrict__ out,
                                                   const int* __restrict__ gid,
                                                   float* __restrict__ gsum,
                                                   const float* __restrict__ normv,
                                                   const float* __restrict__ rnorm) {
    __shared__ float red4[4][128];
    int tid = threadIdx.x;
    int lane = tid & 63;
    int wid = tid >> 6;
    int l15 = lane & 15;
    int lk = lane >> 4;                 // 0..3
    int n0 = blockIdx.x * 128;
    int rbase = n0 + wid * 32;

    float4v acc[2][8];
#pragma unroll
    for (int rt = 0; rt < 2; ++rt)
#pragma unroll
        for (int ct = 0; ct < 8; ++ct)
#pragma unroll
            for (int i = 0; i < 4; ++i) acc[rt][ct][i] = 0.f;

    const unsigned short* Aseg[3] = {A0, A1, A2};
#pragma unroll
    for (int ks = 0; ks < 12; ++ks) {
        const unsigned short* A = Aseg[ks >> 2];
        int kloc = (ks & 3) * 32 + lk * 8;
        short8v a0 = *(const short8v*)(A + (size_t)(rbase + l15) * 128 + kloc);
        short8v a1 = *(const short8v*)(A + (size_t)(rbase + 16 + l15) * 128 + kloc);
        const unsigned short* wp = Wt + (size_t)l15 * 384 + ks * 32 + lk * 8;
#pragma unroll
        for (int ct = 0; ct < 8; ++ct) {
            short8v b = *(const short8v*)(wp + (size_t)ct * 16 * 384);
            acc[0][ct] = __builtin_amdgcn_mfma_f32_16x16x32_bf16(a0, b, acc[0][ct], 0, 0, 0);
            acc[1][ct] = __builtin_amdgcn_mfma_f32_16x16x32_bf16(a1, b, acc[1][ct], 0, 0, 0);
        }
    }

    if (!POOL) {
        // C/D: col=lane&15, row=(lane>>4)*4+reg
        float bj[8];
#pragma unroll
        for (int ct = 0; ct < 8; ++ct) bj[ct] = bias[ct * 16 + l15];
#pragma unroll
        for (int rt = 0; rt < 2; ++rt)
#pragma unroll
            for (int i = 0; i < 4; ++i) {
                int row = rbase + rt * 16 + lk * 4 + i;
                if (row < N_NODES) {
                    float nv = normv[row];
#pragma unroll
                    for (int ct = 0; ct < 8; ++ct) {
                        float v = acc[rt][ct][i] + nv * bj[ct];
                        if (RELU) v = fmaxf(v, 0.f);
                        out[(size_t)row * 128 + ct * 16 + l15] = (unsigned short)f2bf(v);
                    }
                }
            }
    } else {
        int gr[2][4];
        float rn[2][4];
#pragma unroll
        for (int rt = 0; rt < 2; ++rt)
#pragma unroll
            for (int i = 0; i < 4; ++i) {
                int row = rbase + rt * 16 + lk * 4 + i;
                bool ok = (row < N_NODES);
                gr[rt][i] = ok ? gid[row] : -1;
                rn[rt][i] = ok ? rnorm[row] : 0.f;
            }
        int lastrow = n0 + 127;
        if (lastrow >= N_NODES) lastrow = N_NODES - 1;
        int gfirst = gid[n0];
        int glast = gid[lastrow];
        for (int g = gfirst; g <= glast; ++g) {
            float p[8];
#pragma unroll
            for (int ct = 0; ct < 8; ++ct) {
                float s = 0.f;
#pragma unroll
                for (int rt = 0; rt < 2; ++rt)
#pragma unroll
                    for (int i = 0; i < 4; ++i)
                        if (gr[rt][i] == g) s += rn[rt][i] * acc[rt][ct][i];
                p[ct] = s;
            }
#pragma unroll
            for (int ct = 0; ct < 8; ++ct) {
                p[ct] += __shfl_xor(p[ct], 16, 64);
                p[ct] += __shfl_xor(p[ct], 32, 64);
            }
            if (lane < 16) {
#pragma unroll
                for (int ct = 0; ct < 8; ++ct) red4[wid][ct * 16 + lane] = p[ct];
            }
            __syncthreads();
            if (tid < 128) {
                float s = red4[0][tid] + red4[1][tid] + red4[2][tid] + red4[3][tid];
                atomicAdd(&gsum[g * 128 + tid], s);
            }
            __syncthreads();
        }
    }
}

// ---------- final: counts from run-starts; combined = gsum/cnt + b2 ; out = @Wc + bc ----------
__global__ void k_final(const float* __restrict__ gsum, const int* __restrict__ gstart,
                        const float* __restrict__ b2, const float* __restrict__ perm,
                        const float* __restrict__ Wc, const float* __restrict__ bc,
                        float* __restrict__ out) {
    int t = threadIdx.x;
    if (t >= B_GRAPHS * NCLS) return;
    int b = t / NCLS, c = t % NCLS;
    int s = gstart[b];
    float cf = 1.f;
    bool nonempty = (s >= 0);
    if (nonempty) {
        int nxt = N_NODES;
        for (int j = b + 1; j < B_GRAPHS; ++j) {
            int sj = gstart[j];
            if (sj >= 0) { nxt = sj; break; }
        }
        int cnt = nxt - s;
        cf = (cnt < 1) ? 1.f : (float)cnt;
    }
    float acc = bc[c];
    for (int d = 0; d < DH; ++d) {
        float hg = gsum[b * 128 + d] / cf + (nonempty ? b2[d] : 0.f);
        acc += hg * Wc[d * NCLS + c];
    }
    for (int p = 0; p < PFEAT; ++p) acc += perm[b * PFEAT + p] * Wc[(DH + p) * NCLS + c];
    out[t] = acc;
}

extern "C" void kernel_launch(void* const* d_in, const int* in_sizes, int n_in,
                              void* d_out, int out_size, void* d_ws, size_t ws_size,
                              hipStream_t stream) {
    const float* h    = (const float*)d_in[0];
    const int*   src  = (const int*)d_in[1];
    const int*   dst  = (const int*)d_in[2];
    const int*   gid  = (const int*)d_in[3];
    const float* perm = (const float*)d_in[4];
    const float* W1   = (const float*)d_in[5];
    const float* b1   = (const float*)d_in[6];
    const float* W2   = (const float*)d_in[7];
    const float* b2   = (const float*)d_in[8];
    const float* Wc   = (const float*)d_in[9];
    const float* bc   = (const float*)d_in[10];
    float* out = (float*)d_out;

    char* ws = (char*)d_ws;
    size_t off = 0;
    auto alloc = [&](size_t bytes) {
        void* p = ws + off;
        off = (off + bytes + 255) & ~(size_t)255;
        return p;
    };
    int*   deg     = (int*)alloc(N_NODES * 4);
    int*   row_ptr = (int*)alloc((N_NODES + 1) * 4);
    int*   col     = (int*)alloc(N_EDGES * 4);
    int*   epos    = (int*)alloc(N_EDGES * 4);
    int*   bsum    = (int*)alloc(SCAN_BLOCKS * 4);
    float* norm    = (float*)alloc(N_NODES * 4);
    float* rnorm   = (float*)alloc(N_NODES * 4);
    unsigned short* h_bf = (unsigned short*)alloc((size_t)NPAD * 128 * 2);
    unsigned short* f1   = (unsigned short*)alloc((size_t)NPAD * 128 * 2);
    unsigned short* f2   = (unsigned short*)alloc((size_t)NPAD * 128 * 2);
    unsigned short* x2   = (unsigned short*)alloc((size_t)NPAD * 128 * 2);
    unsigned short* Wt1  = (unsigned short*)alloc(384 * 128 * 2);
    unsigned short* Wt2  = (unsigned short*)alloc(384 * 128 * 2);
    float* gsum    = (float*)alloc(B_GRAPHS * 128 * 4);
    int*   gstart  = (int*)alloc(B_GRAPHS * 4);

    // init: zeroing + W transposes + pad-row zeroing (grid covers 2*WELEMS)
    k_init<<<(2 * WELEMS + 255) / 256, 256, 0, stream>>>(W1, W2, Wt1, Wt2,
                                                         deg, gsum, gstart,
                                                         h_bf, f1, f2, x2);
    // CSR build
    k_deg_bound<<<(N_EDGES + N_NODES + 255) / 256, 256, 0, stream>>>(dst, gid, deg, epos, gstart);
    k_norm_bsum<<<SCAN_BLOCKS, 256, 0, stream>>>(deg, norm, rnorm, bsum);
    k_scan2<<<SCAN_BLOCKS, 256, 0, stream>>>(deg, bsum, row_ptr);
    // scatter + h->bf16 (pre-scaled by norm) fused
    k_scatter_cvt<<<(NCVT4 + 255) / 256, 256, 0, stream>>>(src, dst, row_ptr, epos, col,
                                                           h, norm, h_bf);

    int spmm_grid = (N_NODES + 3) / 4;
    int gemm_grid = (N_NODES + 127) / 128;

    // Layer 1 (scaled domain): y1 = A y0, y2 = A y1, x2(scaled) = relu-gemm
    k_spmm<<<spmm_grid, 256, 0, stream>>>(h_bf, norm, row_ptr, col, f1);
    k_spmm<<<spmm_grid, 256, 0, stream>>>(f1, norm, row_ptr, col, f2);
    k_gemm_mfma<true, false><<<gemm_grid, 256, 0, stream>>>(h_bf, f1, f2, Wt1, b1, x2,
                                                            gid, gsum, norm, rnorm);

    // Layer 2: hops on scaled x2, pool-gemm unscales per row
    k_spmm<<<spmm_grid, 256, 0, stream>>>(x2, norm, row_ptr, col, f1);
    k_spmm<<<spmm_grid, 256, 0, stream>>>(f1, norm, row_ptr, col, f2);
    k_gemm_mfma<false, true><<<gemm_grid, 256, 0, stream>>>(x2, f1, f2, Wt2, nullptr, nullptr,
                                                            gid, gsum, norm, rnorm);

    // Readout
    k_final<<<1, 128, 0, stream>>>(gsum, gstart, b2, perm, Wc, bc, out);
}

// Round 12
// 227.422 us; speedup vs baseline: 1.4618x; 1.0732x over previous
//
#include <hip/hip_runtime.h>

#define N_NODES 50000
#define N_EDGES 600000
#define B_GRAPHS 64
#define DH 128
#define PFEAT 32
#define NCLS 2
#define SCAN_BLOCKS ((N_NODES + 255) / 256)   // 196
#define NPAD (N_NODES + 128)                  // row padding (row N_NODES = zero row)
#define NCVT4 (N_NODES * 128 / 4)             // 1,600,000 float4 chunks
#define WELEMS (384 * 128)                    // 49,152

typedef __attribute__((ext_vector_type(8))) short short8v;
typedef __attribute__((ext_vector_type(4))) float float4v;
typedef __attribute__((ext_vector_type(4))) unsigned int uint4v;

__device__ __forceinline__ unsigned int f2bf(float f) {
    unsigned int u = __float_as_uint(f);
    return (u + 0x7FFFu + ((u >> 16) & 1u)) >> 16;   // RNE
}
__device__ __forceinline__ float bflo(unsigned int p) { return __uint_as_float(p << 16); }
__device__ __forceinline__ float bfhi(unsigned int p) { return __uint_as_float(p & 0xFFFF0000u); }

// ---------- init: zero scratch + W1/W2 transpose-convert + zero pad rows ----------
__global__ void k_init(const float* __restrict__ W1, const float* __restrict__ W2,
                       unsigned short* __restrict__ Wt1, unsigned short* __restrict__ Wt2,
                       int* __restrict__ deg, float* __restrict__ gsum,
                       int* __restrict__ gstart,
                       unsigned short* __restrict__ h_bf, unsigned short* __restrict__ f1,
                       unsigned short* __restrict__ f2, unsigned short* __restrict__ x2) {
    int t = blockIdx.x * 256 + threadIdx.x;
    if (t < 2 * WELEMS) {
        bool second = (t >= WELEMS);
        int idx = second ? t - WELEMS : t;
        const float* W = second ? W2 : W1;
        unsigned short* Wt = second ? Wt2 : Wt1;
        int k = idx >> 7, c = idx & 127;
        Wt[c * 384 + k] = (unsigned short)f2bf(W[idx]);
    }
    if (t < N_NODES) deg[t] = 0;
    if (t < B_GRAPHS * DH) gsum[t] = 0.f;
    if (t < B_GRAPHS) gstart[t] = -1;
    if (t < 4 * 32) {  // zero row N_NODES of each feature buffer (clamp target)
        unsigned short* bufs[4] = {h_bf, f1, f2, x2};
        uint2 z; z.x = 0u; z.y = 0u;
        ((uint2*)(bufs[t >> 5] + (size_t)N_NODES * 128))[t & 31] = z;
    }
}

// ---------- fused: degree atomics (saving bucket positions) + graph run-starts ----------
__global__ void k_deg_bound(const int* __restrict__ dst, const int* __restrict__ gid,
                            int* __restrict__ deg, int* __restrict__ epos,
                            int* __restrict__ gstart) {
    int t = blockIdx.x * 256 + threadIdx.x;
    if (t < N_EDGES) {
        int pos = atomicAdd(&deg[dst[t]], 1);
        epos[t] = pos;
    }
    int n = t - N_EDGES;
    if (n >= 0 && n < N_NODES) {
        int g = gid[n];
        if (n == 0 || gid[n - 1] != g) gstart[g] = n;
    }
}

// ---------- fused: norm + rnorm + per-block degree sums ----------
__global__ void k_norm_bsum(const int* __restrict__ deg, float* __restrict__ norm,
                            float* __restrict__ rnorm, int* __restrict__ bsum) {
    __shared__ int s[256];
    int i = blockIdx.x * 256 + threadIdx.x;
    int d = (i < N_NODES) ? deg[i] : 0;
    if (i < N_NODES) {
        int dc = d < 1 ? 1 : d;
        norm[i] = rsqrtf((float)dc);
        rnorm[i] = sqrtf((float)dc);
    }
    s[threadIdx.x] = d;
    __syncthreads();
    for (int off = 128; off > 0; off >>= 1) {
        if (threadIdx.x < off) s[threadIdx.x] += s[threadIdx.x + off];
        __syncthreads();
    }
    if (threadIdx.x == 0) bsum[blockIdx.x] = s[0];
}

// ---------- scan: each block redundantly scans 196 block-sums in LDS + local scan ----------
__global__ void k_scan2(const int* __restrict__ deg, const int* __restrict__ bsum,
                        int* __restrict__ row_ptr) {
    __shared__ int sb[256];
    __shared__ int s[256];
    int bv = (threadIdx.x < SCAN_BLOCKS) ? bsum[threadIdx.x] : 0;
    sb[threadIdx.x] = bv;
    int i = blockIdx.x * 256 + threadIdx.x;
    int v = (i < N_NODES) ? deg[i] : 0;
    s[threadIdx.x] = v;
    __syncthreads();
    for (int off = 1; off < 256; off <<= 1) {
        int tb = (threadIdx.x >= off) ? sb[threadIdx.x - off] : 0;
        int t = (threadIdx.x >= off) ? s[threadIdx.x - off] : 0;
        __syncthreads();
        sb[threadIdx.x] += tb;
        s[threadIdx.x] += t;
        __syncthreads();
    }
    int block_off = (blockIdx.x == 0) ? 0 : sb[blockIdx.x - 1];
    if (i < N_NODES) row_ptr[i + 1] = s[threadIdx.x] + block_off;
    if (i == 0) row_ptr[0] = 0;
}

// ---------- fused: atomic-free scatter + h -> bf16 pre-scaled by norm ----------
__global__ void k_scatter_cvt(const int* __restrict__ src, const int* __restrict__ dst,
                              const int* __restrict__ row_ptr, const int* __restrict__ epos,
                              int* __restrict__ col, const float* __restrict__ h,
                              const float* __restrict__ norm,
                              unsigned short* __restrict__ h_bf) {
    int t = blockIdx.x * 256 + threadIdx.x;
    if (t < N_EDGES) {
        int d = dst[t];
        col[row_ptr[d] + epos[t]] = src[t];
    }
    if (t < NCVT4) {
        float4 v = ((const float4*)h)[t];
        float nv = norm[t >> 5];                 // 32 float4 chunks per 128-wide row
        unsigned int lo = f2bf(v.x * nv) | (f2bf(v.y * nv) << 16);
        unsigned int hi = f2bf(v.z * nv) | (f2bf(v.w * nv) << 16);
        uint2 r; r.x = lo; r.y = hi;
        ((uint2*)h_bf)[t] = r;
    }
}

// ---------- SpMM hop, row-per-group: y_out[v] = norm[v]^2 * sum y_in[u] ----------
// Block = 256 thr = 16 groups x 16 lanes; each group owns one row v.
// Lane l15 owns columns l15*8..+7 (16B). 4-deep edge pipeline per group
// (16 gathers in flight per wave). No cross-lane reduction; all lanes store.
__global__ __launch_bounds__(256) void k_spmm(const unsigned short* __restrict__ fin,
                                              const float* __restrict__ norm,
                                              const int* __restrict__ row_ptr,
                                              const int* __restrict__ col,
                                              unsigned short* __restrict__ fout) {
    int tid = threadIdx.x;
    int grp = tid >> 4;        // 0..15
    int l15 = tid & 15;
    int v = blockIdx.x * 16 + grp;
    if (v >= N_NODES) return;
    int beg = row_ptr[v], end = row_ptr[v + 1];

    float a0[8], a1[8], a2[8], a3[8];
#pragma unroll
    for (int j = 0; j < 8; ++j) { a0[j] = 0.f; a1[j] = 0.f; a2[j] = 0.f; a3[j] = 0.f; }

    int last = end - 1;
    for (int e = beg; e < end; e += 4) {
        int e1 = e + 1, e2 = e + 2, e3 = e + 3;
        int u0 = col[e];
        int u1 = col[(e1 < end) ? e1 : last];
        int u2 = col[(e2 < end) ? e2 : last];
        int u3 = col[(e3 < end) ? e3 : last];
        u1 = (e1 < end) ? u1 : N_NODES;   // OOB -> zero pad row
        u2 = (e2 < end) ? u2 : N_NODES;
        u3 = (e3 < end) ? u3 : N_NODES;
        uint4v r0 = *(const uint4v*)(fin + (size_t)u0 * 128 + l15 * 8);
        uint4v r1 = *(const uint4v*)(fin + (size_t)u1 * 128 + l15 * 8);
        uint4v r2 = *(const uint4v*)(fin + (size_t)u2 * 128 + l15 * 8);
        uint4v r3 = *(const uint4v*)(fin + (size_t)u3 * 128 + l15 * 8);
#pragma unroll
        for (int q = 0; q < 4; ++q) {
            a0[2 * q]     += bflo(r0[q]);
            a0[2 * q + 1] += bfhi(r0[q]);
            a1[2 * q]     += bflo(r1[q]);
            a1[2 * q + 1] += bfhi(r1[q]);
            a2[2 * q]     += bflo(r2[q]);
            a2[2 * q + 1] += bfhi(r2[q]);
            a3[2 * q]     += bflo(r3[q]);
            a3[2 * q + 1] += bfhi(r3[q]);
        }
    }

    float nv = norm[v];
    float s2 = nv * nv;
    uint4v o;
#pragma unroll
    for (int q = 0; q < 4; ++q) {
        float lo = (a0[2 * q] + a1[2 * q]) + (a2[2 * q] + a3[2 * q]);
        float hi = (a0[2 * q + 1] + a1[2 * q + 1]) + (a2[2 * q + 1] + a3[2 * q + 1]);
        o[q] = f2bf(lo * s2) | (f2bf(hi * s2) << 16);
    }
    *(uint4v*)(fout + (size_t)v * 128 + l15 * 8) = o;
}

// ---------- bf16 MFMA GEMM on scaled features: wave = 32 rows x 128 cols ----------
// acc_row = norm[row] * ([x|Ax|A2x]@W)_row.
// RELU path:  write relu(acc + norm*b)  (stays in scaled domain for next layer)
// POOL path:  pool rnorm[row]*acc (unscaled), bias deferred to k_final
template <bool RELU, bool POOL>
__global__ __launch_bounds__(256) void k_gemm_mfma(const unsigned short* __restrict__ A0,
                                                   const unsigned short* __restrict__ A1,
                                                   const unsigned short* __restrict__ A2,
                                                   const unsigned short* __restrict__ Wt,
                                                   const float* __restrict__ bias,
                                                   unsigned short* __restrict__ out,
                                                   const int* __restrict__ gid,
                                                   float* __restrict__ gsum,
                                                   const float* __restrict__ normv,
                                                   const float* __restrict__ rnorm) {
    __shared__ float red4[4][128];
    int tid = threadIdx.x;
    int lane = tid & 63;
    int wid = tid >> 6;
    int l15 = lane & 15;
    int lk = lane >> 4;                 // 0..3
    int n0 = blockIdx.x * 128;
    int rbase = n0 + wid * 32;

    float4v acc[2][8];
#pragma unroll
    for (int rt = 0; rt < 2; ++rt)
#pragma unroll
        for (int ct = 0; ct < 8; ++ct)
#pragma unroll
            for (int i = 0; i < 4; ++i) acc[rt][ct][i] = 0.f;

    const unsigned short* Aseg[3] = {A0, A1, A2};
#pragma unroll
    for (int ks = 0; ks < 12; ++ks) {
        const unsigned short* A = Aseg[ks >> 2];
        int kloc = (ks & 3) * 32 + lk * 8;
        short8v a0 = *(const short8v*)(A + (size_t)(rbase + l15) * 128 + kloc);
        short8v a1 = *(const short8v*)(A + (size_t)(rbase + 16 + l15) * 128 + kloc);
        const unsigned short* wp = Wt + (size_t)l15 * 384 + ks * 32 + lk * 8;
#pragma unroll
        for (int ct = 0; ct < 8; ++ct) {
            short8v b = *(const short8v*)(wp + (size_t)ct * 16 * 384);
            acc[0][ct] = __builtin_amdgcn_mfma_f32_16x16x32_bf16(a0, b, acc[0][ct], 0, 0, 0);
            acc[1][ct] = __builtin_amdgcn_mfma_f32_16x16x32_bf16(a1, b, acc[1][ct], 0, 0, 0);
        }
    }

    if (!POOL) {
        // C/D: col=lane&15, row=(lane>>4)*4+reg
        float bj[8];
#pragma unroll
        for (int ct = 0; ct < 8; ++ct) bj[ct] = bias[ct * 16 + l15];
#pragma unroll
        for (int rt = 0; rt < 2; ++rt)
#pragma unroll
            for (int i = 0; i < 4; ++i) {
                int row = rbase + rt * 16 + lk * 4 + i;
                if (row < N_NODES) {
                    float nv = normv[row];
#pragma unroll
                    for (int ct = 0; ct < 8; ++ct) {
                        float v = acc[rt][ct][i] + nv * bj[ct];
                        if (RELU) v = fmaxf(v, 0.f);
                        out[(size_t)row * 128 + ct * 16 + l15] = (unsigned short)f2bf(v);
                    }
                }
            }
    } else {
        int gr[2][4];
        float rn[2][4];
#pragma unroll
        for (int rt = 0; rt < 2; ++rt)
#pragma unroll
            for (int i = 0; i < 4; ++i) {
                int row = rbase + rt * 16 + lk * 4 + i;
                bool ok = (row < N_NODES);
                gr[rt][i] = ok ? gid[row] : -1;
                rn[rt][i] = ok ? rnorm[row] : 0.f;
            }
        int lastrow = n0 + 127;
        if (lastrow >= N_NODES) lastrow = N_NODES - 1;
        int gfirst = gid[n0];
        int glast = gid[lastrow];
        for (int g = gfirst; g <= glast; ++g) {
            float p[8];
#pragma unroll
            for (int ct = 0; ct < 8; ++ct) {
                float s = 0.f;
#pragma unroll
                for (int rt = 0; rt < 2; ++rt)
#pragma unroll
                    for (int i = 0; i < 4; ++i)
                        if (gr[rt][i] == g) s += rn[rt][i] * acc[rt][ct][i];
                p[ct] = s;
            }
#pragma unroll
            for (int ct = 0; ct < 8; ++ct) {
                p[ct] += __shfl_xor(p[ct], 16, 64);
                p[ct] += __shfl_xor(p[ct], 32, 64);
            }
            if (lane < 16) {
#pragma unroll
                for (int ct = 0; ct < 8; ++ct) red4[wid][ct * 16 + lane] = p[ct];
            }
            __syncthreads();
            if (tid < 128) {
                float s = red4[0][tid] + red4[1][tid] + red4[2][tid] + red4[3][tid];
                atomicAdd(&gsum[g * 128 + tid], s);
            }
            __syncthreads();
        }
    }
}

// ---------- final: counts from run-starts; combined = gsum/cnt + b2 ; out = @Wc + bc ----------
__global__ void k_final(const float* __restrict__ gsum, const int* __restrict__ gstart,
                        const float* __restrict__ b2, const float* __restrict__ perm,
                        const float* __restrict__ Wc, const float* __restrict__ bc,
                        float* __restrict__ out) {
    int t = threadIdx.x;
    if (t >= B_GRAPHS * NCLS) return;
    int b = t / NCLS, c = t % NCLS;
    int s = gstart[b];
    float cf = 1.f;
    bool nonempty = (s >= 0);
    if (nonempty) {
        int nxt = N_NODES;
        for (int j = b + 1; j < B_GRAPHS; ++j) {
            int sj = gstart[j];
            if (sj >= 0) { nxt = sj; break; }
        }
        int cnt = nxt - s;
        cf = (cnt < 1) ? 1.f : (float)cnt;
    }
    float acc = bc[c];
    for (int d = 0; d < DH; ++d) {
        float hg = gsum[b * 128 + d] / cf + (nonempty ? b2[d] : 0.f);
        acc += hg * Wc[d * NCLS + c];
    }
    for (int p = 0; p < PFEAT; ++p) acc += perm[b * PFEAT + p] * Wc[(DH + p) * NCLS + c];
    out[t] = acc;
}

extern "C" void kernel_launch(void* const* d_in, const int* in_sizes, int n_in,
                              void* d_out, int out_size, void* d_ws, size_t ws_size,
                              hipStream_t stream) {
    const float* h    = (const float*)d_in[0];
    const int*   src  = (const int*)d_in[1];
    const int*   dst  = (const int*)d_in[2];
    const int*   gid  = (const int*)d_in[3];
    const float* perm = (const float*)d_in[4];
    const float* W1   = (const float*)d_in[5];
    const float* b1   = (const float*)d_in[6];
    const float* W2   = (const float*)d_in[7];
    const float* b2   = (const float*)d_in[8];
    const float* Wc   = (const float*)d_in[9];
    const float* bc   = (const float*)d_in[10];
    float* out = (float*)d_out;

    char* ws = (char*)d_ws;
    size_t off = 0;
    auto alloc = [&](size_t bytes) {
        void* p = ws + off;
        off = (off + bytes + 255) & ~(size_t)255;
        return p;
    };
    int*   deg     = (int*)alloc(N_NODES * 4);
    int*   row_ptr = (int*)alloc((N_NODES + 1) * 4);
    int*   col     = (int*)alloc(N_EDGES * 4);
    int*   epos    = (int*)alloc(N_EDGES * 4);
    int*   bsum    = (int*)alloc(SCAN_BLOCKS * 4);
    float* norm    = (float*)alloc(N_NODES * 4);
    float* rnorm   = (float*)alloc(N_NODES * 4);
    unsigned short* h_bf = (unsigned short*)alloc((size_t)NPAD * 128 * 2);
    unsigned short* f1   = (unsigned short*)alloc((size_t)NPAD * 128 * 2);
    unsigned short* f2   = (unsigned short*)alloc((size_t)NPAD * 128 * 2);
    unsigned short* x2   = (unsigned short*)alloc((size_t)NPAD * 128 * 2);
    unsigned short* Wt1  = (unsigned short*)alloc(384 * 128 * 2);
    unsigned short* Wt2  = (unsigned short*)alloc(384 * 128 * 2);
    float* gsum    = (float*)alloc(B_GRAPHS * 128 * 4);
    int*   gstart  = (int*)alloc(B_GRAPHS * 4);

    // init: zeroing + W transposes + pad-row zeroing (grid covers 2*WELEMS)
    k_init<<<(2 * WELEMS + 255) / 256, 256, 0, stream>>>(W1, W2, Wt1, Wt2,
                                                         deg, gsum, gstart,
                                                         h_bf, f1, f2, x2);
    // CSR build
    k_deg_bound<<<(N_EDGES + N_NODES + 255) / 256, 256, 0, stream>>>(dst, gid, deg, epos, gstart);
    k_norm_bsum<<<SCAN_BLOCKS, 256, 0, stream>>>(deg, norm, rnorm, bsum);
    k_scan2<<<SCAN_BLOCKS, 256, 0, stream>>>(deg, bsum, row_ptr);
    // scatter + h->bf16 (pre-scaled by norm) fused
    k_scatter_cvt<<<(NCVT4 + 255) / 256, 256, 0, stream>>>(src, dst, row_ptr, epos, col,
                                                           h, norm, h_bf);

    int spmm_grid = (N_NODES + 15) / 16;   // 3125 (16 rows per block)
    int gemm_grid = (N_NODES + 127) / 128;

    // Layer 1 (scaled domain): y1 = A y0, y2 = A y1, x2(scaled) = relu-gemm
    k_spmm<<<spmm_grid, 256, 0, stream>>>(h_bf, norm, row_ptr, col, f1);
    k_spmm<<<spmm_grid, 256, 0, stream>>>(f1, norm, row_ptr, col, f2);
    k_gemm_mfma<true, false><<<gemm_grid, 256, 0, stream>>>(h_bf, f1, f2, Wt1, b1, x2,
                                                            gid, gsum, norm, rnorm);

    // Layer 2: hops on scaled x2, pool-gemm unscales per row
    k_spmm<<<spmm_grid, 256, 0, stream>>>(x2, norm, row_ptr, col, f1);
    k_spmm<<<spmm_grid, 256, 0, stream>>>(f1, norm, row_ptr, col, f2);
    k_gemm_mfma<false, true><<<gemm_grid, 256, 0, stream>>>(x2, f1, f2, Wt2, nullptr, nullptr,
                                                            gid, gsum, norm, rnorm);

    // Readout
    k_final<<<1, 128, 0, stream>>>(gsum, gstart, b2, perm, Wc, bc, out);
}

// Round 13
// 227.143 us; speedup vs baseline: 1.4636x; 1.0012x over previous
//
#include <hip/hip_runtime.h>

#define N_NODES 50000
#define N_EDGES 600000
#define B_GRAPHS 64
#define DH 128
#define PFEAT 32
#define NCLS 2
#define SCAN_BLOCKS ((N_NODES + 255) / 256)   // 196
#define NPAD (N_NODES + 128)                  // row padding (row N_NODES = zero row)
#define NCVT4 (N_NODES * 128 / 4)             // 1,600,000 float4 chunks
#define WELEMS (384 * 128)                    // 49,152

typedef __attribute__((ext_vector_type(8))) short short8v;
typedef __attribute__((ext_vector_type(4))) float float4v;
typedef __attribute__((ext_vector_type(4))) unsigned int uint4v;

__device__ __forceinline__ unsigned int f2bf(float f) {
    unsigned int u = __float_as_uint(f);
    return (u + 0x7FFFu + ((u >> 16) & 1u)) >> 16;   // RNE
}
__device__ __forceinline__ float bflo(unsigned int p) { return __uint_as_float(p << 16); }
__device__ __forceinline__ float bfhi(unsigned int p) { return __uint_as_float(p & 0xFFFF0000u); }

// ---------- init: zero scratch + W1/W2 transpose-convert + zero pad rows ----------
__global__ void k_init(const float* __restrict__ W1, const float* __restrict__ W2,
                       unsigned short* __restrict__ Wt1, unsigned short* __restrict__ Wt2,
                       int* __restrict__ deg, float* __restrict__ gsum,
                       int* __restrict__ gstart,
                       unsigned short* __restrict__ h_bf, unsigned short* __restrict__ f1,
                       unsigned short* __restrict__ f2, unsigned short* __restrict__ x2) {
    int t = blockIdx.x * 256 + threadIdx.x;
    if (t < 2 * WELEMS) {
        bool second = (t >= WELEMS);
        int idx = second ? t - WELEMS : t;
        const float* W = second ? W2 : W1;
        unsigned short* Wt = second ? Wt2 : Wt1;
        int k = idx >> 7, c = idx & 127;
        Wt[c * 384 + k] = (unsigned short)f2bf(W[idx]);
    }
    if (t < N_NODES) deg[t] = 0;
    if (t < B_GRAPHS * DH) gsum[t] = 0.f;
    if (t < B_GRAPHS) gstart[t] = -1;
    if (t < 4 * 32) {  // zero row N_NODES of each feature buffer (clamp target)
        unsigned short* bufs[4] = {h_bf, f1, f2, x2};
        uint2 z; z.x = 0u; z.y = 0u;
        ((uint2*)(bufs[t >> 5] + (size_t)N_NODES * 128))[t & 31] = z;
    }
}

// ---------- fused: degree atomics (saving bucket positions) + graph run-starts ----------
__global__ void k_deg_bound(const int* __restrict__ dst, const int* __restrict__ gid,
                            int* __restrict__ deg, int* __restrict__ epos,
                            int* __restrict__ gstart) {
    int t = blockIdx.x * 256 + threadIdx.x;
    if (t < N_EDGES) {
        int pos = atomicAdd(&deg[dst[t]], 1);
        epos[t] = pos;
    }
    int n = t - N_EDGES;
    if (n >= 0 && n < N_NODES) {
        int g = gid[n];
        if (n == 0 || gid[n - 1] != g) gstart[g] = n;
    }
}

// ---------- fused: norm + rnorm + per-block degree sums ----------
__global__ void k_norm_bsum(const int* __restrict__ deg, float* __restrict__ norm,
                            float* __restrict__ rnorm, int* __restrict__ bsum) {
    __shared__ int s[256];
    int i = blockIdx.x * 256 + threadIdx.x;
    int d = (i < N_NODES) ? deg[i] : 0;
    if (i < N_NODES) {
        int dc = d < 1 ? 1 : d;
        norm[i] = rsqrtf((float)dc);
        rnorm[i] = sqrtf((float)dc);
    }
    s[threadIdx.x] = d;
    __syncthreads();
    for (int off = 128; off > 0; off >>= 1) {
        if (threadIdx.x < off) s[threadIdx.x] += s[threadIdx.x + off];
        __syncthreads();
    }
    if (threadIdx.x == 0) bsum[blockIdx.x] = s[0];
}

// ---------- scan: each block redundantly scans 196 block-sums in LDS + local scan ----------
__global__ void k_scan2(const int* __restrict__ deg, const int* __restrict__ bsum,
                        int* __restrict__ row_ptr) {
    __shared__ int sb[256];
    __shared__ int s[256];
    int bv = (threadIdx.x < SCAN_BLOCKS) ? bsum[threadIdx.x] : 0;
    sb[threadIdx.x] = bv;
    int i = blockIdx.x * 256 + threadIdx.x;
    int v = (i < N_NODES) ? deg[i] : 0;
    s[threadIdx.x] = v;
    __syncthreads();
    for (int off = 1; off < 256; off <<= 1) {
        int tb = (threadIdx.x >= off) ? sb[threadIdx.x - off] : 0;
        int t = (threadIdx.x >= off) ? s[threadIdx.x - off] : 0;
        __syncthreads();
        sb[threadIdx.x] += tb;
        s[threadIdx.x] += t;
        __syncthreads();
    }
    int block_off = (blockIdx.x == 0) ? 0 : sb[blockIdx.x - 1];
    if (i < N_NODES) row_ptr[i + 1] = s[threadIdx.x] + block_off;
    if (i == 0) row_ptr[0] = 0;
}

// ---------- fused: atomic-free scatter + h -> bf16 pre-scaled by norm ----------
__global__ void k_scatter_cvt(const int* __restrict__ src, const int* __restrict__ dst,
                              const int* __restrict__ row_ptr, const int* __restrict__ epos,
                              int* __restrict__ col, const float* __restrict__ h,
                              const float* __restrict__ norm,
                              unsigned short* __restrict__ h_bf) {
    int t = blockIdx.x * 256 + threadIdx.x;
    if (t < N_EDGES) {
        int d = dst[t];
        col[row_ptr[d] + epos[t]] = src[t];
    }
    if (t < NCVT4) {
        float4 v = ((const float4*)h)[t];
        float nv = norm[t >> 5];                 // 32 float4 chunks per 128-wide row
        unsigned int lo = f2bf(v.x * nv) | (f2bf(v.y * nv) << 16);
        unsigned int hi = f2bf(v.z * nv) | (f2bf(v.w * nv) << 16);
        uint2 r; r.x = lo; r.y = hi;
        ((uint2*)h_bf)[t] = r;
    }
}

// ---------- SpMM hop, row-per-group: y_out[v] = norm[v]^2 * sum y_in[u] ----------
// Block = 256 thr = 16 groups x 16 lanes; each group owns one row v.
// Lane l15 owns columns l15*8..+7 (16B). 4-deep edge pipeline per group
// (16 gathers in flight per wave). No cross-lane reduction; all lanes store.
__global__ __launch_bounds__(256) void k_spmm(const unsigned short* __restrict__ fin,
                                              const float* __restrict__ norm,
                                              const int* __restrict__ row_ptr,
                                              const int* __restrict__ col,
                                              unsigned short* __restrict__ fout) {
    int tid = threadIdx.x;
    int grp = tid >> 4;        // 0..15
    int l15 = tid & 15;
    int v = blockIdx.x * 16 + grp;
    if (v >= N_NODES) return;
    int beg = row_ptr[v], end = row_ptr[v + 1];

    float a0[8], a1[8], a2[8], a3[8];
#pragma unroll
    for (int j = 0; j < 8; ++j) { a0[j] = 0.f; a1[j] = 0.f; a2[j] = 0.f; a3[j] = 0.f; }

    int last = end - 1;
    for (int e = beg; e < end; e += 4) {
        int e1 = e + 1, e2 = e + 2, e3 = e + 3;
        int u0 = col[e];
        int u1 = col[(e1 < end) ? e1 : last];
        int u2 = col[(e2 < end) ? e2 : last];
        int u3 = col[(e3 < end) ? e3 : last];
        u1 = (e1 < end) ? u1 : N_NODES;   // OOB -> zero pad row
        u2 = (e2 < end) ? u2 : N_NODES;
        u3 = (e3 < end) ? u3 : N_NODES;
        uint4v r0 = *(const uint4v*)(fin + (size_t)u0 * 128 + l15 * 8);
        uint4v r1 = *(const uint4v*)(fin + (size_t)u1 * 128 + l15 * 8);
        uint4v r2 = *(const uint4v*)(fin + (size_t)u2 * 128 + l15 * 8);
        uint4v r3 = *(const uint4v*)(fin + (size_t)u3 * 128 + l15 * 8);
#pragma unroll
        for (int q = 0; q < 4; ++q) {
            a0[2 * q]     += bflo(r0[q]);
            a0[2 * q + 1] += bfhi(r0[q]);
            a1[2 * q]     += bflo(r1[q]);
            a1[2 * q + 1] += bfhi(r1[q]);
            a2[2 * q]     += bflo(r2[q]);
            a2[2 * q + 1] += bfhi(r2[q]);
            a3[2 * q]     += bflo(r3[q]);
            a3[2 * q + 1] += bfhi(r3[q]);
        }
    }

    float nv = norm[v];
    float s2 = nv * nv;
    uint4v o;
#pragma unroll
    for (int q = 0; q < 4; ++q) {
        float lo = (a0[2 * q] + a1[2 * q]) + (a2[2 * q] + a3[2 * q]);
        float hi = (a0[2 * q + 1] + a1[2 * q + 1]) + (a2[2 * q + 1] + a3[2 * q + 1]);
        o[q] = f2bf(lo * s2) | (f2bf(hi * s2) << 16);
    }
    *(uint4v*)(fout + (size_t)v * 128 + l15 * 8) = o;
}

// ---------- bf16 MFMA GEMM on scaled features: wave = 32 rows x 128 cols ----------
// Grid-limited occupancy (391 blocks = 1.5 waves/SIMD) => VGPRs are free.
// __launch_bounds__(256, 1) unlocks the full register file so the compiler can
// prefetch the fully-unrolled k-loop's loads many iterations deep.
template <bool RELU, bool POOL>
__global__ __launch_bounds__(256, 1) void k_gemm_mfma(const unsigned short* __restrict__ A0,
                                                      const unsigned short* __restrict__ A1,
                                                      const unsigned short* __restrict__ A2,
                                                      const unsigned short* __restrict__ Wt,
                                                      const float* __restrict__ bias,
                                                      unsigned short* __restrict__ out,
                                                      const int* __restrict__ gid,
                                                      float* __restrict__ gsum,
                                                      const float* __restrict__ normv,
                                                      const float* __restrict__ rnorm) {
    __shared__ float red4[4][128];
    int tid = threadIdx.x;
    int lane = tid & 63;
    int wid = tid >> 6;
    int l15 = lane & 15;
    int lk = lane >> 4;                 // 0..3
    int n0 = blockIdx.x * 128;
    int rbase = n0 + wid * 32;

    float4v acc[2][8];
#pragma unroll
    for (int rt = 0; rt < 2; ++rt)
#pragma unroll
        for (int ct = 0; ct < 8; ++ct)
#pragma unroll
            for (int i = 0; i < 4; ++i) acc[rt][ct][i] = 0.f;

    const unsigned short* Aseg[3] = {A0, A1, A2};
#pragma unroll
    for (int ks = 0; ks < 12; ++ks) {
        const unsigned short* A = Aseg[ks >> 2];
        int kloc = (ks & 3) * 32 + lk * 8;
        short8v a0 = *(const short8v*)(A + (size_t)(rbase + l15) * 128 + kloc);
        short8v a1 = *(const short8v*)(A + (size_t)(rbase + 16 + l15) * 128 + kloc);
        const unsigned short* wp = Wt + (size_t)l15 * 384 + ks * 32 + lk * 8;
#pragma unroll
        for (int ct = 0; ct < 8; ++ct) {
            short8v b = *(const short8v*)(wp + (size_t)ct * 16 * 384);
            acc[0][ct] = __builtin_amdgcn_mfma_f32_16x16x32_bf16(a0, b, acc[0][ct], 0, 0, 0);
            acc[1][ct] = __builtin_amdgcn_mfma_f32_16x16x32_bf16(a1, b, acc[1][ct], 0, 0, 0);
        }
    }

    if (!POOL) {
        // C/D: col=lane&15, row=(lane>>4)*4+reg
        float bj[8];
#pragma unroll
        for (int ct = 0; ct < 8; ++ct) bj[ct] = bias[ct * 16 + l15];
#pragma unroll
        for (int rt = 0; rt < 2; ++rt)
#pragma unroll
            for (int i = 0; i < 4; ++i) {
                int row = rbase + rt * 16 + lk * 4 + i;
                if (row < N_NODES) {
                    float nv = normv[row];
#pragma unroll
                    for (int ct = 0; ct < 8; ++ct) {
                        float v = acc[rt][ct][i] + nv * bj[ct];
                        if (RELU) v = fmaxf(v, 0.f);
                        out[(size_t)row * 128 + ct * 16 + l15] = (unsigned short)f2bf(v);
                    }
                }
            }
    } else {
        int gr[2][4];
        float rn[2][4];
#pragma unroll
        for (int rt = 0; rt < 2; ++rt)
#pragma unroll
            for (int i = 0; i < 4; ++i) {
                int row = rbase + rt * 16 + lk * 4 + i;
                bool ok = (row < N_NODES);
                gr[rt][i] = ok ? gid[row] : -1;
                rn[rt][i] = ok ? rnorm[row] : 0.f;
            }
        int lastrow = n0 + 127;
        if (lastrow >= N_NODES) lastrow = N_NODES - 1;
        int gfirst = gid[n0];
        int glast = gid[lastrow];
        for (int g = gfirst; g <= glast; ++g) {
            float p[8];
#pragma unroll
            for (int ct = 0; ct < 8; ++ct) {
                float s = 0.f;
#pragma unroll
                for (int rt = 0; rt < 2; ++rt)
#pragma unroll
                    for (int i = 0; i < 4; ++i)
                        if (gr[rt][i] == g) s += rn[rt][i] * acc[rt][ct][i];
                p[ct] = s;
            }
#pragma unroll
            for (int ct = 0; ct < 8; ++ct) {
                p[ct] += __shfl_xor(p[ct], 16, 64);
                p[ct] += __shfl_xor(p[ct], 32, 64);
            }
            if (lane < 16) {
#pragma unroll
                for (int ct = 0; ct < 8; ++ct) red4[wid][ct * 16 + lane] = p[ct];
            }
            __syncthreads();
            if (tid < 128) {
                float s = red4[0][tid] + red4[1][tid] + red4[2][tid] + red4[3][tid];
                atomicAdd(&gsum[g * 128 + tid], s);
            }
            __syncthreads();
        }
    }
}

// ---------- final: counts from run-starts; combined = gsum/cnt + b2 ; out = @Wc + bc ----------
__global__ void k_final(const float* __restrict__ gsum, const int* __restrict__ gstart,
                        const float* __restrict__ b2, const float* __restrict__ perm,
                        const float* __restrict__ Wc, const float* __restrict__ bc,
                        float* __restrict__ out) {
    int t = threadIdx.x;
    if (t >= B_GRAPHS * NCLS) return;
    int b = t / NCLS, c = t % NCLS;
    int s = gstart[b];
    float cf = 1.f;
    bool nonempty = (s >= 0);
    if (nonempty) {
        int nxt = N_NODES;
        for (int j = b + 1; j < B_GRAPHS; ++j) {
            int sj = gstart[j];
            if (sj >= 0) { nxt = sj; break; }
        }
        int cnt = nxt - s;
        cf = (cnt < 1) ? 1.f : (float)cnt;
    }
    float acc = bc[c];
    for (int d = 0; d < DH; ++d) {
        float hg = gsum[b * 128 + d] / cf + (nonempty ? b2[d] : 0.f);
        acc += hg * Wc[d * NCLS + c];
    }
    for (int p = 0; p < PFEAT; ++p) acc += perm[b * PFEAT + p] * Wc[(DH + p) * NCLS + c];
    out[t] = acc;
}

extern "C" void kernel_launch(void* const* d_in, const int* in_sizes, int n_in,
                              void* d_out, int out_size, void* d_ws, size_t ws_size,
                              hipStream_t stream) {
    const float* h    = (const float*)d_in[0];
    const int*   src  = (const int*)d_in[1];
    const int*   dst  = (const int*)d_in[2];
    const int*   gid  = (const int*)d_in[3];
    const float* perm = (const float*)d_in[4];
    const float* W1   = (const float*)d_in[5];
    const float* b1   = (const float*)d_in[6];
    const float* W2   = (const float*)d_in[7];
    const float* b2   = (const float*)d_in[8];
    const float* Wc   = (const float*)d_in[9];
    const float* bc   = (const float*)d_in[10];
    float* out = (float*)d_out;

    char* ws = (char*)d_ws;
    size_t off = 0;
    auto alloc = [&](size_t bytes) {
        void* p = ws + off;
        off = (off + bytes + 255) & ~(size_t)255;
        return p;
    };
    int*   deg     = (int*)alloc(N_NODES * 4);
    int*   row_ptr = (int*)alloc((N_NODES + 1) * 4);
    int*   col     = (int*)alloc(N_EDGES * 4);
    int*   epos    = (int*)alloc(N_EDGES * 4);
    int*   bsum    = (int*)alloc(SCAN_BLOCKS * 4);
    float* norm    = (float*)alloc(N_NODES * 4);
    float* rnorm   = (float*)alloc(N_NODES * 4);
    unsigned short* h_bf = (unsigned short*)alloc((size_t)NPAD * 128 * 2);
    unsigned short* f1   = (unsigned short*)alloc((size_t)NPAD * 128 * 2);
    unsigned short* f2   = (unsigned short*)alloc((size_t)NPAD * 128 * 2);
    unsigned short* x2   = (unsigned short*)alloc((size_t)NPAD * 128 * 2);
    unsigned short* Wt1  = (unsigned short*)alloc(384 * 128 * 2);
    unsigned short* Wt2  = (unsigned short*)alloc(384 * 128 * 2);
    float* gsum    = (float*)alloc(B_GRAPHS * 128 * 4);
    int*   gstart  = (int*)alloc(B_GRAPHS * 4);

    // init: zeroing + W transposes + pad-row zeroing (grid covers 2*WELEMS)
    k_init<<<(2 * WELEMS + 255) / 256, 256, 0, stream>>>(W1, W2, Wt1, Wt2,
                                                         deg, gsum, gstart,
                                                         h_bf, f1, f2, x2);
    // CSR build
    k_deg_bound<<<(N_EDGES + N_NODES + 255) / 256, 256, 0, stream>>>(dst, gid, deg, epos, gstart);
    k_norm_bsum<<<SCAN_BLOCKS, 256, 0, stream>>>(deg, norm, rnorm, bsum);
    k_scan2<<<SCAN_BLOCKS, 256, 0, stream>>>(deg, bsum, row_ptr);
    // scatter + h->bf16 (pre-scaled by norm) fused
    k_scatter_cvt<<<(NCVT4 + 255) / 256, 256, 0, stream>>>(src, dst, row_ptr, epos, col,
                                                           h, norm, h_bf);

    int spmm_grid = (N_NODES + 15) / 16;   // 3125 (16 rows per block)
    int gemm_grid = (N_NODES + 127) / 128;

    // Layer 1 (scaled domain): y1 = A y0, y2 = A y1, x2(scaled) = relu-gemm
    k_spmm<<<spmm_grid, 256, 0, stream>>>(h_bf, norm, row_ptr, col, f1);
    k_spmm<<<spmm_grid, 256, 0, stream>>>(f1, norm, row_ptr, col, f2);
    k_gemm_mfma<true, false><<<gemm_grid, 256, 0, stream>>>(h_bf, f1, f2, Wt1, b1, x2,
                                                            gid, gsum, norm, rnorm);

    // Layer 2: hops on scaled x2, pool-gemm unscales per row
    k_spmm<<<spmm_grid, 256, 0, stream>>>(x2, norm, row_ptr, col, f1);
    k_spmm<<<spmm_grid, 256, 0, stream>>>(f1, norm, row_ptr, col, f2);
    k_gemm_mfma<false, true><<<gemm_grid, 256, 0, stream>>>(x2, f1, f2, Wt2, nullptr, nullptr,
                                                            gid, gsum, norm, rnorm);

    // Readout
    k_final<<<1, 128, 0, stream>>>(gsum, gstart, b2, perm, Wc, bc, out);
}

// Round 14
// 226.825 us; speedup vs baseline: 1.4657x; 1.0014x over previous
//
#include <hip/hip_runtime.h>

#define N_NODES 50000
#define N_EDGES 600000
#define B_GRAPHS 64
#define DH 128
#define PFEAT 32
#define NCLS 2
#define SCAN_BLOCKS ((N_NODES + 255) / 256)   // 196
#define NPAD (N_NODES + 128)                  // row padding (row N_NODES = zero row)
#define NCVT4 (N_NODES * 128 / 4)             // 1,600,000 float4 chunks
#define WELEMS (384 * 128)                    // 49,152

typedef __attribute__((ext_vector_type(8))) short short8v;
typedef __attribute__((ext_vector_type(4))) float float4v;
typedef __attribute__((ext_vector_type(4))) unsigned int uint4v;

__device__ __forceinline__ unsigned int f2bf(float f) {
    unsigned int u = __float_as_uint(f);
    return (u + 0x7FFFu + ((u >> 16) & 1u)) >> 16;   // RNE
}
__device__ __forceinline__ float bflo(unsigned int p) { return __uint_as_float(p << 16); }
__device__ __forceinline__ float bfhi(unsigned int p) { return __uint_as_float(p & 0xFFFF0000u); }

// ---------- init: zero scratch + W1/W2 transpose-convert + zero pad rows ----------
__global__ void k_init(const float* __restrict__ W1, const float* __restrict__ W2,
                       unsigned short* __restrict__ Wt1, unsigned short* __restrict__ Wt2,
                       int* __restrict__ deg, float* __restrict__ gsum,
                       int* __restrict__ gstart,
                       unsigned short* __restrict__ h_bf, unsigned short* __restrict__ f1,
                       unsigned short* __restrict__ f2, unsigned short* __restrict__ x2) {
    int t = blockIdx.x * 256 + threadIdx.x;
    if (t < 2 * WELEMS) {
        bool second = (t >= WELEMS);
        int idx = second ? t - WELEMS : t;
        const float* W = second ? W2 : W1;
        unsigned short* Wt = second ? Wt2 : Wt1;
        int k = idx >> 7, c = idx & 127;
        Wt[c * 384 + k] = (unsigned short)f2bf(W[idx]);
    }
    if (t < N_NODES) deg[t] = 0;
    if (t < B_GRAPHS * DH) gsum[t] = 0.f;
    if (t < B_GRAPHS) gstart[t] = -1;
    if (t < 4 * 32) {  // zero row N_NODES of each feature buffer (clamp target)
        unsigned short* bufs[4] = {h_bf, f1, f2, x2};
        uint2 z; z.x = 0u; z.y = 0u;
        ((uint2*)(bufs[t >> 5] + (size_t)N_NODES * 128))[t & 31] = z;
    }
}

// ---------- fused: degree atomics (saving bucket positions) + graph run-starts ----------
__global__ void k_deg_bound(const int* __restrict__ dst, const int* __restrict__ gid,
                            int* __restrict__ deg, int* __restrict__ epos,
                            int* __restrict__ gstart) {
    int t = blockIdx.x * 256 + threadIdx.x;
    if (t < N_EDGES) {
        int pos = atomicAdd(&deg[dst[t]], 1);
        epos[t] = pos;
    }
    int n = t - N_EDGES;
    if (n >= 0 && n < N_NODES) {
        int g = gid[n];
        if (n == 0 || gid[n - 1] != g) gstart[g] = n;
    }
}

// ---------- fused: norm + rnorm + per-block degree sums ----------
__global__ void k_norm_bsum(const int* __restrict__ deg, float* __restrict__ norm,
                            float* __restrict__ rnorm, int* __restrict__ bsum) {
    __shared__ int s[256];
    int i = blockIdx.x * 256 + threadIdx.x;
    int d = (i < N_NODES) ? deg[i] : 0;
    if (i < N_NODES) {
        int dc = d < 1 ? 1 : d;
        norm[i] = rsqrtf((float)dc);
        rnorm[i] = sqrtf((float)dc);
    }
    s[threadIdx.x] = d;
    __syncthreads();
    for (int off = 128; off > 0; off >>= 1) {
        if (threadIdx.x < off) s[threadIdx.x] += s[threadIdx.x + off];
        __syncthreads();
    }
    if (threadIdx.x == 0) bsum[blockIdx.x] = s[0];
}

// ---------- scan: each block redundantly scans 196 block-sums in LDS + local scan ----------
__global__ void k_scan2(const int* __restrict__ deg, const int* __restrict__ bsum,
                        int* __restrict__ row_ptr) {
    __shared__ int sb[256];
    __shared__ int s[256];
    int bv = (threadIdx.x < SCAN_BLOCKS) ? bsum[threadIdx.x] : 0;
    sb[threadIdx.x] = bv;
    int i = blockIdx.x * 256 + threadIdx.x;
    int v = (i < N_NODES) ? deg[i] : 0;
    s[threadIdx.x] = v;
    __syncthreads();
    for (int off = 1; off < 256; off <<= 1) {
        int tb = (threadIdx.x >= off) ? sb[threadIdx.x - off] : 0;
        int t = (threadIdx.x >= off) ? s[threadIdx.x - off] : 0;
        __syncthreads();
        sb[threadIdx.x] += tb;
        s[threadIdx.x] += t;
        __syncthreads();
    }
    int block_off = (blockIdx.x == 0) ? 0 : sb[blockIdx.x - 1];
    if (i < N_NODES) row_ptr[i + 1] = s[threadIdx.x] + block_off;
    if (i == 0) row_ptr[0] = 0;
}

// ---------- fused: atomic-free scatter + h -> bf16 pre-scaled by norm ----------
__global__ void k_scatter_cvt(const int* __restrict__ src, const int* __restrict__ dst,
                              const int* __restrict__ row_ptr, const int* __restrict__ epos,
                              int* __restrict__ col, const float* __restrict__ h,
                              const float* __restrict__ norm,
                              unsigned short* __restrict__ h_bf) {
    int t = blockIdx.x * 256 + threadIdx.x;
    if (t < N_EDGES) {
        int d = dst[t];
        col[row_ptr[d] + epos[t]] = src[t];
    }
    if (t < NCVT4) {
        float4 v = ((const float4*)h)[t];
        float nv = norm[t >> 5];                 // 32 float4 chunks per 128-wide row
        unsigned int lo = f2bf(v.x * nv) | (f2bf(v.y * nv) << 16);
        unsigned int hi = f2bf(v.z * nv) | (f2bf(v.w * nv) << 16);
        uint2 r; r.x = lo; r.y = hi;
        ((uint2*)h_bf)[t] = r;
    }
}

// ---------- SpMM hop, row-per-group: y_out[v] = norm[v]^2 * sum y_in[u] ----------
__global__ __launch_bounds__(256) void k_spmm(const unsigned short* __restrict__ fin,
                                              const float* __restrict__ norm,
                                              const int* __restrict__ row_ptr,
                                              const int* __restrict__ col,
                                              unsigned short* __restrict__ fout) {
    int tid = threadIdx.x;
    int grp = tid >> 4;        // 0..15
    int l15 = tid & 15;
    int v = blockIdx.x * 16 + grp;
    if (v >= N_NODES) return;
    int beg = row_ptr[v], end = row_ptr[v + 1];

    float a0[8], a1[8], a2[8], a3[8];
#pragma unroll
    for (int j = 0; j < 8; ++j) { a0[j] = 0.f; a1[j] = 0.f; a2[j] = 0.f; a3[j] = 0.f; }

    int last = end - 1;
    for (int e = beg; e < end; e += 4) {
        int e1 = e + 1, e2 = e + 2, e3 = e + 3;
        int u0 = col[e];
        int u1 = col[(e1 < end) ? e1 : last];
        int u2 = col[(e2 < end) ? e2 : last];
        int u3 = col[(e3 < end) ? e3 : last];
        u1 = (e1 < end) ? u1 : N_NODES;   // OOB -> zero pad row
        u2 = (e2 < end) ? u2 : N_NODES;
        u3 = (e3 < end) ? u3 : N_NODES;
        uint4v r0 = *(const uint4v*)(fin + (size_t)u0 * 128 + l15 * 8);
        uint4v r1 = *(const uint4v*)(fin + (size_t)u1 * 128 + l15 * 8);
        uint4v r2 = *(const uint4v*)(fin + (size_t)u2 * 128 + l15 * 8);
        uint4v r3 = *(const uint4v*)(fin + (size_t)u3 * 128 + l15 * 8);
#pragma unroll
        for (int q = 0; q < 4; ++q) {
            a0[2 * q]     += bflo(r0[q]);
            a0[2 * q + 1] += bfhi(r0[q]);
            a1[2 * q]     += bflo(r1[q]);
            a1[2 * q + 1] += bfhi(r1[q]);
            a2[2 * q]     += bflo(r2[q]);
            a2[2 * q + 1] += bfhi(r2[q]);
            a3[2 * q]     += bflo(r3[q]);
            a3[2 * q + 1] += bfhi(r3[q]);
        }
    }

    float nv = norm[v];
    float s2 = nv * nv;
    uint4v o;
#pragma unroll
    for (int q = 0; q < 4; ++q) {
        float lo = (a0[2 * q] + a1[2 * q]) + (a2[2 * q] + a3[2 * q]);
        float hi = (a0[2 * q + 1] + a1[2 * q + 1]) + (a2[2 * q + 1] + a3[2 * q + 1]);
        o[q] = f2bf(lo * s2) | (f2bf(hi * s2) << 16);
    }
    *(uint4v*)(fout + (size_t)v * 128 + l15 * 8) = o;
}

// ---------- bf16 MFMA GEMM, 2-way K-split: 8 waves = 4 row-groups x 2 K-halves ----------
// Block = 512 thr = 8 waves; waves 0-3 do ks 0..5, waves 4-7 do ks 6..11 on the
// SAME 128 rows. Upper waves dump partial acc to LDS (lane-major, conflict-free),
// zero their acc; lower waves add. Halves each wave's dependent-load chain and
// doubles waves/SIMD for latency hiding. Grid = 391.
template <bool RELU, bool POOL>
__global__ __launch_bounds__(512, 1) void k_gemm_mfma(const unsigned short* __restrict__ A0,
                                                      const unsigned short* __restrict__ A1,
                                                      const unsigned short* __restrict__ A2,
                                                      const unsigned short* __restrict__ Wt,
                                                      const float* __restrict__ bias,
                                                      unsigned short* __restrict__ out,
                                                      const int* __restrict__ gid,
                                                      float* __restrict__ gsum,
                                                      const float* __restrict__ normv,
                                                      const float* __restrict__ rnorm) {
    __shared__ float comb[4][64 * 64];   // 64 KB: upper-half partial accumulators
    __shared__ float red8[8][128];       // pool reduction
    int tid = threadIdx.x;
    int lane = tid & 63;
    int wid = tid >> 6;                  // 0..7
    int rg = wid & 3;                    // row group 0..3
    int khalf = wid >> 2;                // 0 or 1
    int l15 = lane & 15;
    int lk = lane >> 4;                  // 0..3
    int n0 = blockIdx.x * 128;
    int rbase = n0 + rg * 32;

    float4v acc[2][8];
#pragma unroll
    for (int rt = 0; rt < 2; ++rt)
#pragma unroll
        for (int ct = 0; ct < 8; ++ct)
#pragma unroll
            for (int i = 0; i < 4; ++i) acc[rt][ct][i] = 0.f;

    const unsigned short* Aseg[3] = {A0, A1, A2};
#pragma unroll
    for (int s = 0; s < 6; ++s) {
        int ks = khalf * 6 + s;
        const unsigned short* A = Aseg[ks >> 2];
        int kloc = (ks & 3) * 32 + lk * 8;
        short8v a0 = *(const short8v*)(A + (size_t)(rbase + l15) * 128 + kloc);
        short8v a1 = *(const short8v*)(A + (size_t)(rbase + 16 + l15) * 128 + kloc);
        const unsigned short* wp = Wt + (size_t)l15 * 384 + ks * 32 + lk * 8;
#pragma unroll
        for (int ct = 0; ct < 8; ++ct) {
            short8v b = *(const short8v*)(wp + (size_t)ct * 16 * 384);
            acc[0][ct] = __builtin_amdgcn_mfma_f32_16x16x32_bf16(a0, b, acc[0][ct], 0, 0, 0);
            acc[1][ct] = __builtin_amdgcn_mfma_f32_16x16x32_bf16(a1, b, acc[1][ct], 0, 0, 0);
        }
    }

    // K-split combine: upper waves -> LDS (lane-major: consecutive lanes, consecutive banks)
    if (khalf == 1) {
#pragma unroll
        for (int rt = 0; rt < 2; ++rt)
#pragma unroll
            for (int ct = 0; ct < 8; ++ct)
#pragma unroll
                for (int i = 0; i < 4; ++i) {
                    int idx = rt * 32 + ct * 4 + i;
                    comb[rg][idx * 64 + lane] = acc[rt][ct][i];
                    acc[rt][ct][i] = 0.f;
                }
    }
    __syncthreads();
    if (khalf == 0) {
#pragma unroll
        for (int rt = 0; rt < 2; ++rt)
#pragma unroll
            for (int ct = 0; ct < 8; ++ct)
#pragma unroll
                for (int i = 0; i < 4; ++i) {
                    int idx = rt * 32 + ct * 4 + i;
                    acc[rt][ct][i] += comb[rg][idx * 64 + lane];
                }
    }

    if (!POOL) {
        // epilogue by lower waves only (upper hold zeros). C/D: col=l15, row=lk*4+i
        if (khalf == 0) {
            float bj[8];
#pragma unroll
            for (int ct = 0; ct < 8; ++ct) bj[ct] = bias[ct * 16 + l15];
#pragma unroll
            for (int rt = 0; rt < 2; ++rt)
#pragma unroll
                for (int i = 0; i < 4; ++i) {
                    int row = rbase + rt * 16 + lk * 4 + i;
                    if (row < N_NODES) {
                        float nv = normv[row];
#pragma unroll
                        for (int ct = 0; ct < 8; ++ct) {
                            float v = acc[rt][ct][i] + nv * bj[ct];
                            if (RELU) v = fmaxf(v, 0.f);
                            out[(size_t)row * 128 + ct * 16 + l15] = (unsigned short)f2bf(v);
                        }
                    }
                }
        }
    } else {
        // fused mean-pool numerator; ALL 8 waves run the barrier loop
        // (upper waves contribute zeros since their acc was zeroed)
        int gr[2][4];
        float rn[2][4];
#pragma unroll
        for (int rt = 0; rt < 2; ++rt)
#pragma unroll
            for (int i = 0; i < 4; ++i) {
                int row = rbase + rt * 16 + lk * 4 + i;
                bool ok = (row < N_NODES);
                gr[rt][i] = ok ? gid[row] : -1;
                rn[rt][i] = ok ? rnorm[row] : 0.f;
            }
        int lastrow = n0 + 127;
        if (lastrow >= N_NODES) lastrow = N_NODES - 1;
        int gfirst = gid[n0];
        int glast = gid[lastrow];
        for (int g = gfirst; g <= glast; ++g) {
            float p[8];
#pragma unroll
            for (int ct = 0; ct < 8; ++ct) {
                float s = 0.f;
#pragma unroll
                for (int rt = 0; rt < 2; ++rt)
#pragma unroll
                    for (int i = 0; i < 4; ++i)
                        if (gr[rt][i] == g) s += rn[rt][i] * acc[rt][ct][i];
                p[ct] = s;
            }
#pragma unroll
            for (int ct = 0; ct < 8; ++ct) {
                p[ct] += __shfl_xor(p[ct], 16, 64);
                p[ct] += __shfl_xor(p[ct], 32, 64);
            }
            if (lane < 16) {
#pragma unroll
                for (int ct = 0; ct < 8; ++ct) red8[wid][ct * 16 + lane] = p[ct];
            }
            __syncthreads();
            if (tid < 128) {
                float s = 0.f;
#pragma unroll
                for (int w = 0; w < 8; ++w) s += red8[w][tid];
                atomicAdd(&gsum[g * 128 + tid], s);
            }
            __syncthreads();
        }
    }
}

// ---------- final: counts from run-starts; combined = gsum/cnt + b2 ; out = @Wc + bc ----------
__global__ void k_final(const float* __restrict__ gsum, const int* __restrict__ gstart,
                        const float* __restrict__ b2, const float* __restrict__ perm,
                        const float* __restrict__ Wc, const float* __restrict__ bc,
                        float* __restrict__ out) {
    int t = threadIdx.x;
    if (t >= B_GRAPHS * NCLS) return;
    int b = t / NCLS, c = t % NCLS;
    int s = gstart[b];
    float cf = 1.f;
    bool nonempty = (s >= 0);
    if (nonempty) {
        int nxt = N_NODES;
        for (int j = b + 1; j < B_GRAPHS; ++j) {
            int sj = gstart[j];
            if (sj >= 0) { nxt = sj; break; }
        }
        int cnt = nxt - s;
        cf = (cnt < 1) ? 1.f : (float)cnt;
    }
    float acc = bc[c];
    for (int d = 0; d < DH; ++d) {
        float hg = gsum[b * 128 + d] / cf + (nonempty ? b2[d] : 0.f);
        acc += hg * Wc[d * NCLS + c];
    }
    for (int p = 0; p < PFEAT; ++p) acc += perm[b * PFEAT + p] * Wc[(DH + p) * NCLS + c];
    out[t] = acc;
}

extern "C" void kernel_launch(void* const* d_in, const int* in_sizes, int n_in,
                              void* d_out, int out_size, void* d_ws, size_t ws_size,
                              hipStream_t stream) {
    const float* h    = (const float*)d_in[0];
    const int*   src  = (const int*)d_in[1];
    const int*   dst  = (const int*)d_in[2];
    const int*   gid  = (const int*)d_in[3];
    const float* perm = (const float*)d_in[4];
    const float* W1   = (const float*)d_in[5];
    const float* b1   = (const float*)d_in[6];
    const float* W2   = (const float*)d_in[7];
    const float* b2   = (const float*)d_in[8];
    const float* Wc   = (const float*)d_in[9];
    const float* bc   = (const float*)d_in[10];
    float* out = (float*)d_out;

    char* ws = (char*)d_ws;
    size_t off = 0;
    auto alloc = [&](size_t bytes) {
        void* p = ws + off;
        off = (off + bytes + 255) & ~(size_t)255;
        return p;
    };
    int*   deg     = (int*)alloc(N_NODES * 4);
    int*   row_ptr = (int*)alloc((N_NODES + 1) * 4);
    int*   col     = (int*)alloc(N_EDGES * 4);
    int*   epos    = (int*)alloc(N_EDGES * 4);
    int*   bsum    = (int*)alloc(SCAN_BLOCKS * 4);
    float* norm    = (float*)alloc(N_NODES * 4);
    float* rnorm   = (float*)alloc(N_NODES * 4);
    unsigned short* h_bf = (unsigned short*)alloc((size_t)NPAD * 128 * 2);
    unsigned short* f1   = (unsigned short*)alloc((size_t)NPAD * 128 * 2);
    unsigned short* f2   = (unsigned short*)alloc((size_t)NPAD * 128 * 2);
    unsigned short* x2   = (unsigned short*)alloc((size_t)NPAD * 128 * 2);
    unsigned short* Wt1  = (unsigned short*)alloc(384 * 128 * 2);
    unsigned short* Wt2  = (unsigned short*)alloc(384 * 128 * 2);
    float* gsum    = (float*)alloc(B_GRAPHS * 128 * 4);
    int*   gstart  = (int*)alloc(B_GRAPHS * 4);

    // init: zeroing + W transposes + pad-row zeroing (grid covers 2*WELEMS)
    k_init<<<(2 * WELEMS + 255) / 256, 256, 0, stream>>>(W1, W2, Wt1, Wt2,
                                                         deg, gsum, gstart,
                                                         h_bf, f1, f2, x2);
    // CSR build
    k_deg_bound<<<(N_EDGES + N_NODES + 255) / 256, 256, 0, stream>>>(dst, gid, deg, epos, gstart);
    k_norm_bsum<<<SCAN_BLOCKS, 256, 0, stream>>>(deg, norm, rnorm, bsum);
    k_scan2<<<SCAN_BLOCKS, 256, 0, stream>>>(deg, bsum, row_ptr);
    // scatter + h->bf16 (pre-scaled by norm) fused
    k_scatter_cvt<<<(NCVT4 + 255) / 256, 256, 0, stream>>>(src, dst, row_ptr, epos, col,
                                                           h, norm, h_bf);

    int spmm_grid = (N_NODES + 15) / 16;   // 3125 (16 rows per block)
    int gemm_grid = (N_NODES + 127) / 128; // 391 (128 rows per block, 8 waves)

    // Layer 1 (scaled domain): y1 = A y0, y2 = A y1, x2(scaled) = relu-gemm
    k_spmm<<<spmm_grid, 256, 0, stream>>>(h_bf, norm, row_ptr, col, f1);
    k_spmm<<<spmm_grid, 256, 0, stream>>>(f1, norm, row_ptr, col, f2);
    k_gemm_mfma<true, false><<<gemm_grid, 512, 0, stream>>>(h_bf, f1, f2, Wt1, b1, x2,
                                                            gid, gsum, norm, rnorm);

    // Layer 2: hops on scaled x2, pool-gemm unscales per row
    k_spmm<<<spmm_grid, 256, 0, stream>>>(x2, norm, row_ptr, col, f1);
    k_spmm<<<spmm_grid, 256, 0, stream>>>(f1, norm, row_ptr, col, f2);
    k_gemm_mfma<false, true><<<gemm_grid, 512, 0, stream>>>(x2, f1, f2, Wt2, nullptr, nullptr,
                                                            gid, gsum, norm, rnorm);

    // Readout
    k_final<<<1, 128, 0, stream>>>(gsum, gstart, b2, perm, Wc, bc, out);
}